// Round 4
// baseline (212341.626 us; speedup 1.0000x reference)
//
#include <hip/hip_runtime.h>
#include <math.h>

#define B_SZ 128
#define T_IN 8000
#define T_OUT 1600
#define HDIM 384
#define GDIM 1536   // 4*H
#define TC 100      // time chunk
#define NCHUNK (T_OUT / TC)
#define SPIN_MAX 2048

typedef _Float16 f16;
typedef __attribute__((ext_vector_type(4))) _Float16 f16x4;
typedef __attribute__((ext_vector_type(8))) _Float16 f16x8;

// ---------------------------------------------------------------------------
// conv1 (5,1,4) + silu + conv2 (5,4,16) + silu, fused. One thread per (b,t).
// Output y2 in fp16.
// ---------------------------------------------------------------------------
__global__ __launch_bounds__(256) void conv12_kernel(
    const float* __restrict__ x, const float* __restrict__ w1, const float* __restrict__ b1,
    const float* __restrict__ w2, const float* __restrict__ b2, f16* __restrict__ y2) {
  __shared__ float sw1[20], sb1[4], sw2[320], sb2[16];
  int tid = threadIdx.x;
  if (tid < 20) sw1[tid] = w1[tid];
  if (tid < 4)  sb1[tid] = b1[tid];
  if (tid < 16) sb2[tid] = b2[tid];
  for (int i = tid; i < 320; i += 256) sw2[i] = w2[i];
  __syncthreads();
  int flat = blockIdx.x * 256 + tid;
  int b = flat / T_IN, t = flat % T_IN;
  const float* xb = x + (size_t)b * T_IN;
  float xv[9];
#pragma unroll
  for (int d = 0; d < 9; ++d) {
    int tt = t + d - 4;
    xv[d] = (tt >= 0 && tt < T_IN) ? xb[tt] : 0.f;
  }
  float y1[5][4];
#pragma unroll
  for (int u = 0; u < 5; ++u) {
    int tau = t + u - 2;
    bool valid = (tau >= 0 && tau < T_IN);
#pragma unroll
    for (int co = 0; co < 4; ++co) {
      float a = sb1[co];
#pragma unroll
      for (int k = 0; k < 5; ++k) a = fmaf(xv[u + k], sw1[k * 4 + co], a);
      y1[u][co] = valid ? (a / (1.f + expf(-a))) : 0.f;
    }
  }
  f16x8 o0, o1;
#pragma unroll
  for (int co = 0; co < 16; ++co) {
    float a = sb2[co];
#pragma unroll
    for (int u = 0; u < 5; ++u)
#pragma unroll
      for (int ci = 0; ci < 4; ++ci)
        a = fmaf(y1[u][ci], sw2[(u * 4 + ci) * 16 + co], a);
    float sv = a / (1.f + expf(-a));
    if (co < 8) o0[co] = (f16)sv; else o1[co - 8] = (f16)sv;
  }
  f16x8* dst = (f16x8*)(y2 + (size_t)flat * 16);
  dst[0] = o0;
  dst[1] = o1;
}

// ---------------------------------------------------------------------------
// conv3: (19,16,384), stride 5, SAME (pad 7/7), + silu. fp16 in/out, fp32 math.
// ---------------------------------------------------------------------------
__global__ __launch_bounds__(384) void conv3_kernel(
    const f16* __restrict__ y2, const float* __restrict__ w3, const float* __restrict__ b3,
    f16* __restrict__ act) {
  __shared__ float in_s[94 * 16];
  int tid = threadIdx.x;
  int b = blockIdx.y;
  int t0 = blockIdx.x * 16;
  int base_t = t0 * 5 - 7;
  for (int i = tid; i < 94 * 16; i += 384) {
    int tau = i >> 4, ci = i & 15;
    int tt = base_t + tau;
    in_s[i] = (tt >= 0 && tt < T_IN) ? (float)y2[((size_t)b * T_IN + tt) * 16 + ci] : 0.f;
  }
  __syncthreads();
  int c = tid;
  float acc[16];
  float bv = b3[c];
#pragma unroll
  for (int tt = 0; tt < 16; ++tt) acc[tt] = bv;
  for (int kk = 0; kk < 19; ++kk) {
#pragma unroll
    for (int c4 = 0; c4 < 4; ++c4) {
      float wa = w3[(size_t)((kk * 16 + c4 * 4 + 0) * 384) + c];
      float wb = w3[(size_t)((kk * 16 + c4 * 4 + 1) * 384) + c];
      float wc = w3[(size_t)((kk * 16 + c4 * 4 + 2) * 384) + c];
      float wd = w3[(size_t)((kk * 16 + c4 * 4 + 3) * 384) + c];
#pragma unroll
      for (int tt = 0; tt < 16; ++tt) {
        const float4 iv = *(const float4*)&in_s[(tt * 5 + kk) * 16 + c4 * 4];
        acc[tt] = fmaf(iv.x, wa, acc[tt]);
        acc[tt] = fmaf(iv.y, wb, acc[tt]);
        acc[tt] = fmaf(iv.z, wc, acc[tt]);
        acc[tt] = fmaf(iv.w, wd, acc[tt]);
      }
    }
  }
#pragma unroll
  for (int tt = 0; tt < 16; ++tt) {
    float a = acc[tt];
    a = a / (1.f + expf(-a));
    act[((size_t)b * T_OUT + t0 + tt) * HDIM + c] = (f16)a;
  }
}

// ---------------------------------------------------------------------------
// Chunked xg GEMM: xgc[b*TC+tl, :] = act[b, lo+tl, :] @ Wi (384x1536).
// act fp16, Wi fp32, xgc fp16; fp32 accumulate. 128x128 tile, 8x8 microtile.
// ---------------------------------------------------------------------------
__global__ __launch_bounds__(256) void gemm_xg_kernel(
    const f16* __restrict__ act, const float* __restrict__ Bw,
    f16* __restrict__ C, int lo) {
  __shared__ float As[16 * 132];
  __shared__ float Bs[16 * 128];
  int tid = threadIdx.x;
  int n0 = blockIdx.x * 128;
  int m0 = blockIdx.y * 128;
  int am = tid >> 2;
  int ak = (tid & 3) * 4;
  int bk = tid >> 5;
  int bn = (tid & 31) * 4;
  int row0 = m0 + am, row1 = row0 + 64;
  const f16* Ap0 = act + ((size_t)(row0 / TC) * T_OUT + lo + row0 % TC) * HDIM + ak;
  const f16* Ap1 = act + ((size_t)(row1 / TC) * T_OUT + lo + row1 % TC) * HDIM + ak;
  const float* Bp = Bw + (size_t)bk * GDIM + n0 + bn;
  f16x4 ra0 = *(const f16x4*)Ap0;
  f16x4 ra1 = *(const f16x4*)Ap1;
  float4 rb0 = *(const float4*)Bp;
  float4 rb1 = *(const float4*)(Bp + (size_t)8 * GDIM);
  float acc[8][8];
#pragma unroll
  for (int i = 0; i < 8; ++i)
#pragma unroll
    for (int j = 0; j < 8; ++j) acc[i][j] = 0.f;
  int tx = tid & 15, ty = tid >> 4;
  for (int kt = 0; kt < 24; ++kt) {
    As[(ak + 0) * 132 + am] = (float)ra0[0];
    As[(ak + 1) * 132 + am] = (float)ra0[1];
    As[(ak + 2) * 132 + am] = (float)ra0[2];
    As[(ak + 3) * 132 + am] = (float)ra0[3];
    As[(ak + 0) * 132 + am + 64] = (float)ra1[0];
    As[(ak + 1) * 132 + am + 64] = (float)ra1[1];
    As[(ak + 2) * 132 + am + 64] = (float)ra1[2];
    As[(ak + 3) * 132 + am + 64] = (float)ra1[3];
    *(float4*)&Bs[bk * 128 + bn] = rb0;
    *(float4*)&Bs[(bk + 8) * 128 + bn] = rb1;
    __syncthreads();
    if (kt < 23) {
      Ap0 += 16; Ap1 += 16; Bp += (size_t)16 * GDIM;
      ra0 = *(const f16x4*)Ap0;
      ra1 = *(const f16x4*)Ap1;
      rb0 = *(const float4*)Bp;
      rb1 = *(const float4*)(Bp + (size_t)8 * GDIM);
    }
#pragma unroll
    for (int k = 0; k < 16; ++k) {
      float4 a0 = *(const float4*)&As[k * 132 + ty * 4];
      float4 a1 = *(const float4*)&As[k * 132 + 64 + ty * 4];
      float4 b0 = *(const float4*)&Bs[k * 128 + tx * 4];
      float4 b1 = *(const float4*)&Bs[k * 128 + 64 + tx * 4];
      float av[8] = {a0.x, a0.y, a0.z, a0.w, a1.x, a1.y, a1.z, a1.w};
      float bv[8] = {b0.x, b0.y, b0.z, b0.w, b1.x, b1.y, b1.z, b1.w};
#pragma unroll
      for (int i = 0; i < 8; ++i)
#pragma unroll
        for (int j = 0; j < 8; ++j) acc[i][j] = fmaf(av[i], bv[j], acc[i][j]);
    }
    __syncthreads();
  }
#pragma unroll
  for (int i = 0; i < 8; ++i) {
    int mi = (i < 4) ? (ty * 4 + i) : (64 + ty * 4 + i - 4);
    f16* Cp = C + (size_t)(m0 + mi) * GDIM + n0;
    f16x4 p0, p1;
    p0[0] = (f16)acc[i][0]; p0[1] = (f16)acc[i][1]; p0[2] = (f16)acc[i][2]; p0[3] = (f16)acc[i][3];
    p1[0] = (f16)acc[i][4]; p1[1] = (f16)acc[i][5]; p1[2] = (f16)acc[i][6]; p1[3] = (f16)acc[i][7];
    *(f16x4*)(Cp + tx * 4) = p0;
    *(f16x4*)(Cp + 64 + tx * 4) = p1;
  }
}

// ---------------------------------------------------------------------------
__global__ void zero_ctr_kernel(int* __restrict__ ctr) {
  ctr[threadIdx.x] = 0;
}

// ---------------------------------------------------------------------------
// Chunked persistent LSTM recurrence. 256 blocks x 256 threads.
// 32 groups x 8 WGs; group g owns batches 4g..4g+3; WG wg owns h-cols
// [48wg,48wg+48). Group WGs share bid&7 -> same XCD. BOUNDED spin: if
// co-residency fails, completes with stale data instead of deadlocking.
// ---------------------------------------------------------------------------
__global__ __launch_bounds__(256, 1) void lstm_kernel(
    const f16* __restrict__ xg, const float* __restrict__ Wh,
    const float* __restrict__ bias, f16* __restrict__ act,
    float* __restrict__ c_state, int* __restrict__ ctr,
    int lo, int reverse, int first, int step_base) {
  int tid = threadIdx.x;
  int bid = blockIdx.x;
  int r8 = bid & 7, si = bid >> 3;
  int g = r8 * 4 + (si >> 3);   // 0..31
  int wg = si & 7;              // 0..7
  int bbase = g * 4;
  int jbase = wg * 48;
  int r = tid & 3, cg = tid >> 2;
  __shared__ float h_lds[4 * 400];   // [k-quarter r][batch b][100 pad]
  __shared__ float z_lds[4 * 200];   // [batch b][200 pad], col c = gate*48+j
  __shared__ float bias_s[192];
  float w[3][96];
  {
    int c0 = 3 * cg;
    int gate = c0 / 48;
    int j0 = c0 % 48;
    const float* whp = Wh + (size_t)(96 * r) * GDIM + gate * HDIM + jbase + j0;
#pragma unroll
    for (int k2 = 0; k2 < 96; ++k2) {
      const float* p = whp + (size_t)k2 * GDIM;
      w[0][k2] = p[0]; w[1][k2] = p[1]; w[2][k2] = p[2];
    }
  }
  if (tid < 192) bias_s[tid] = bias[(tid / 48) * HDIM + jbase + (tid % 48)];
  int hb = tid / 48, hj = tid % 48;  // valid for tid<192
  float c_st = 0.f;
  if (first) {
    for (int i = tid; i < 1600; i += 256) h_lds[i] = 0.f;
  } else {
    int tprev = reverse ? (lo + TC) : (lo - 1);
#pragma unroll
    for (int i = 0; i < 6; ++i) {
      int flat = i * 256 + tid;
      int bb = flat / 384, jj = flat % 384;
      unsigned short uu = __hip_atomic_load(
          (const unsigned short*)act + ((size_t)(bbase + bb) * T_OUT + tprev) * HDIM + jj,
          __ATOMIC_RELAXED, __HIP_MEMORY_SCOPE_AGENT);
      union { unsigned short u; f16 h; } cv; cv.u = uu;
      h_lds[(jj / 96) * 400 + bb * 100 + (jj % 96)] = (float)cv.h;
    }
    if (tid < 192) c_st = c_state[(size_t)(bbase + hb) * HDIM + jbase + hj];
  }
  __syncthreads();

  for (int s = 0; s < TC; ++s) {
    int t = reverse ? (lo + TC - 1 - s) : (lo + s);
    int tl = t - lo;
    float acc[3][4];
#pragma unroll
    for (int cc = 0; cc < 3; ++cc)
#pragma unroll
      for (int bb = 0; bb < 4; ++bb) acc[cc][bb] = 0.f;
#pragma unroll
    for (int kk = 0; kk < 96; kk += 4) {
      const float4 h0 = *(const float4*)&h_lds[r * 400 + 0   + kk];
      const float4 h1 = *(const float4*)&h_lds[r * 400 + 100 + kk];
      const float4 h2 = *(const float4*)&h_lds[r * 400 + 200 + kk];
      const float4 h3 = *(const float4*)&h_lds[r * 400 + 300 + kk];
#pragma unroll
      for (int cc = 0; cc < 3; ++cc) {
        const float w0 = w[cc][kk + 0], w1_ = w[cc][kk + 1];
        const float w2_ = w[cc][kk + 2], w3_ = w[cc][kk + 3];
        acc[cc][0] = fmaf(h0.x, w0, acc[cc][0]); acc[cc][0] = fmaf(h0.y, w1_, acc[cc][0]);
        acc[cc][0] = fmaf(h0.z, w2_, acc[cc][0]); acc[cc][0] = fmaf(h0.w, w3_, acc[cc][0]);
        acc[cc][1] = fmaf(h1.x, w0, acc[cc][1]); acc[cc][1] = fmaf(h1.y, w1_, acc[cc][1]);
        acc[cc][1] = fmaf(h1.z, w2_, acc[cc][1]); acc[cc][1] = fmaf(h1.w, w3_, acc[cc][1]);
        acc[cc][2] = fmaf(h2.x, w0, acc[cc][2]); acc[cc][2] = fmaf(h2.y, w1_, acc[cc][2]);
        acc[cc][2] = fmaf(h2.z, w2_, acc[cc][2]); acc[cc][2] = fmaf(h2.w, w3_, acc[cc][2]);
        acc[cc][3] = fmaf(h3.x, w0, acc[cc][3]); acc[cc][3] = fmaf(h3.y, w1_, acc[cc][3]);
        acc[cc][3] = fmaf(h3.z, w2_, acc[cc][3]); acc[cc][3] = fmaf(h3.w, w3_, acc[cc][3]);
      }
    }
#pragma unroll
    for (int cc = 0; cc < 3; ++cc)
#pragma unroll
      for (int bb = 0; bb < 4; ++bb) {
        float v = acc[cc][bb];
        v += __shfl_xor(v, 1);
        v += __shfl_xor(v, 2);
        acc[cc][bb] = v;
      }
    int c0 = 3 * cg;
    float z0 = (r == 0) ? acc[0][0] : (r == 1) ? acc[0][1] : (r == 2) ? acc[0][2] : acc[0][3];
    float z1 = (r == 0) ? acc[1][0] : (r == 1) ? acc[1][1] : (r == 2) ? acc[1][2] : acc[1][3];
    float z2 = (r == 0) ? acc[2][0] : (r == 1) ? acc[2][1] : (r == 2) ? acc[2][2] : acc[2][3];
    z_lds[r * 200 + c0 + 0] = z0;
    z_lds[r * 200 + c0 + 1] = z1;
    z_lds[r * 200 + c0 + 2] = z2;
    __syncthreads();
    if (tid < 192) {
      float zi = z_lds[hb * 200 + hj];
      float zf = z_lds[hb * 200 + 48 + hj];
      float zg = z_lds[hb * 200 + 96 + hj];
      float zo = z_lds[hb * 200 + 144 + hj];
      const f16* xp = xg + ((size_t)(bbase + hb) * TC + tl) * GDIM + jbase + hj;
      zi += (float)xp[0]    + bias_s[hj];
      zf += (float)xp[384]  + bias_s[48 + hj];
      zg += (float)xp[768]  + bias_s[96 + hj];
      zo += (float)xp[1152] + bias_s[144 + hj];
      float ig = 1.f / (1.f + expf(-zi));
      float fg = 1.f / (1.f + expf(-zf));
      float gv = tanhf(zg);
      float og = 1.f / (1.f + expf(-zo));
      c_st = fg * c_st + ig * gv;
      float hv = og * tanhf(c_st);
      union { unsigned short u; f16 h; } cv; cv.h = (f16)hv;
      __hip_atomic_store(
          (unsigned short*)act + ((size_t)(bbase + hb) * T_OUT + t) * HDIM + jbase + hj,
          cv.u, __ATOMIC_RELAXED, __HIP_MEMORY_SCOPE_AGENT);
    }
    __syncthreads();  // drains vmcnt -> h stores in (XCD-local) L2
    if (tid == 0)
      __hip_atomic_fetch_add(ctr + g, 1, __ATOMIC_RELEASE, __HIP_MEMORY_SCOPE_AGENT);
    if (s + 1 < TC) {
      if (tid == 0) {
        int target = 8 * (step_base + s + 1);
        int spins = 0;
        while (__hip_atomic_load(ctr + g, __ATOMIC_RELAXED, __HIP_MEMORY_SCOPE_AGENT) < target &&
               spins < SPIN_MAX) {
          __builtin_amdgcn_s_sleep(2);
          ++spins;
        }
        (void)__hip_atomic_load(ctr + g, __ATOMIC_ACQUIRE, __HIP_MEMORY_SCOPE_AGENT);
      }
      __syncthreads();
#pragma unroll
      for (int i = 0; i < 6; ++i) {
        int flat = i * 256 + tid;
        int bb = flat / 384, jj = flat % 384;
        unsigned short uu = __hip_atomic_load(
            (const unsigned short*)act + ((size_t)(bbase + bb) * T_OUT + t) * HDIM + jj,
            __ATOMIC_RELAXED, __HIP_MEMORY_SCOPE_AGENT);
        union { unsigned short u; f16 h; } cv; cv.u = uu;
        h_lds[(jj / 96) * 400 + bb * 100 + (jj % 96)] = (float)cv.h;
      }
      __syncthreads();
    }
  }
  if (tid < 192) c_state[(size_t)(bbase + hb) * HDIM + jbase + hj] = c_st;
}

// ---------------------------------------------------------------------------
// dense: out(204800,5) = h(204800,384 fp16) @ W(384,5) + b  (fp32 out)
// ---------------------------------------------------------------------------
__global__ __launch_bounds__(256) void dense_kernel(
    const f16* __restrict__ h, const float* __restrict__ dw,
    const float* __restrict__ db, float* __restrict__ out) {
  __shared__ float ws_[1920];
  __shared__ float bs[5];
  int tid = threadIdx.x;
  for (int i = tid; i < 1920; i += 256) ws_[i] = dw[i];
  if (tid < 5) bs[tid] = db[tid];
  __syncthreads();
  size_t flat = (size_t)blockIdx.x * 256 + tid;
  const f16* hp = h + flat * HDIM;
  float acc[5];
#pragma unroll
  for (int o = 0; o < 5; ++o) acc[o] = bs[o];
  for (int d = 0; d < HDIM; d += 4) {
    f16x4 hv = *(const f16x4*)(hp + d);
#pragma unroll
    for (int o = 0; o < 5; ++o) {
      acc[o] = fmaf((float)hv[0], ws_[(d + 0) * 5 + o], acc[o]);
      acc[o] = fmaf((float)hv[1], ws_[(d + 1) * 5 + o], acc[o]);
      acc[o] = fmaf((float)hv[2], ws_[(d + 2) * 5 + o], acc[o]);
      acc[o] = fmaf((float)hv[3], ws_[(d + 3) * 5 + o], acc[o]);
    }
  }
  float* op = out + flat * 5;
#pragma unroll
  for (int o = 0; o < 5; ++o) op[o] = acc[o];
}

// ---------------------------------------------------------------------------
extern "C" void kernel_launch(void* const* d_in, const int* in_sizes, int n_in,
                              void* d_out, int out_size, void* d_ws, size_t ws_size,
                              hipStream_t stream) {
  const float* x  = (const float*)d_in[0];
  const float* w1 = (const float*)d_in[1];
  const float* b1 = (const float*)d_in[2];
  const float* w2 = (const float*)d_in[3];
  const float* b2 = (const float*)d_in[4];
  const float* w3 = (const float*)d_in[5];
  const float* b3 = (const float*)d_in[6];
  const float* Wi = (const float*)d_in[7];
  const float* Wh = (const float*)d_in[8];
  const float* lb = (const float*)d_in[9];
  const float* dw = (const float*)d_in[10];
  const float* db = (const float*)d_in[11];
  float* out = (float*)d_out;
  char* ws = (char*)d_ws;

  // ws layout (total ~197 MB): act fp16 | xgc fp16 | c_state fp32 | ctr
  const size_t ACT_BYTES = (size_t)B_SZ * T_OUT * HDIM * 2;   // 157.3 MB
  const size_t XGC_BYTES = (size_t)B_SZ * TC * GDIM * 2;      // 39.3 MB
  const size_t CST_BYTES = (size_t)B_SZ * HDIM * 4;           // 197 KB
  f16*   act = (f16*)ws;
  f16*   xgc = (f16*)(ws + ACT_BYTES);
  float* cst = (float*)(ws + ACT_BYTES + XGC_BYTES);
  int*   ctr = (int*)(ws + ACT_BYTES + XGC_BYTES + CST_BYTES);
  f16*   y2  = xgc;  // alias: conv12 out (32.8 MB) dead before first gemm

  hipLaunchKernelGGL(conv12_kernel, dim3(B_SZ * T_IN / 256), dim3(256), 0, stream,
                     x, w1, b1, w2, b2, y2);
  hipLaunchKernelGGL(conv3_kernel, dim3(T_OUT / 16, B_SZ), dim3(384), 0, stream,
                     y2, w3, b3, act);
  hipLaunchKernelGGL(zero_ctr_kernel, dim3(1), dim3(64), 0, stream, ctr);

  for (int l = 0; l < 5; ++l) {
    int rev = (l % 2 == 0) ? 1 : 0;
    const float* wi_p = Wi + (size_t)l * HDIM * GDIM;
    const float* wh_p = Wh + (size_t)l * HDIM * GDIM;
    const float* lb_p = lb + (size_t)l * GDIM;
    for (int ci = 0; ci < NCHUNK; ++ci) {
      int lo = rev ? (T_OUT - (ci + 1) * TC) : (ci * TC);
      hipLaunchKernelGGL(gemm_xg_kernel, dim3(GDIM / 128, (B_SZ * TC) / 128), dim3(256), 0, stream,
                         act, wi_p, xgc, lo);
      hipLaunchKernelGGL(lstm_kernel, dim3(256), dim3(256), 0, stream,
                         xgc, wh_p, lb_p, act, cst, ctr,
                         lo, rev, (ci == 0) ? 1 : 0, l * T_OUT + ci * TC);
    }
  }
  hipLaunchKernelGGL(dense_kernel, dim3((B_SZ * T_OUT) / 256), dim3(256), 0, stream,
                     act, dw, db, out);
}

// Round 5
// 177062.646 us; speedup vs baseline: 1.1992x; 1.1992x over previous
//
#include <hip/hip_runtime.h>
#include <math.h>

#define B_SZ 128
#define T_IN 8000
#define T_OUT 1600
#define HDIM 384
#define GDIM 1536   // 4*H
#define TC 100      // time chunk
#define NCHUNK (T_OUT / TC)
#define SPIN_MAX 4096
#define CTR_STRIDE 32   // ints; one 128B cache line per group

typedef _Float16 f16;
typedef __attribute__((ext_vector_type(4))) _Float16 f16x4;
typedef __attribute__((ext_vector_type(8))) _Float16 f16x8;

// ---------------------------------------------------------------------------
// conv1 (5,1,4) + silu + conv2 (5,4,16) + silu, fused. One thread per (b,t).
// ---------------------------------------------------------------------------
__global__ __launch_bounds__(256) void conv12_kernel(
    const float* __restrict__ x, const float* __restrict__ w1, const float* __restrict__ b1,
    const float* __restrict__ w2, const float* __restrict__ b2, f16* __restrict__ y2) {
  __shared__ float sw1[20], sb1[4], sw2[320], sb2[16];
  int tid = threadIdx.x;
  if (tid < 20) sw1[tid] = w1[tid];
  if (tid < 4)  sb1[tid] = b1[tid];
  if (tid < 16) sb2[tid] = b2[tid];
  for (int i = tid; i < 320; i += 256) sw2[i] = w2[i];
  __syncthreads();
  int flat = blockIdx.x * 256 + tid;
  int b = flat / T_IN, t = flat % T_IN;
  const float* xb = x + (size_t)b * T_IN;
  float xv[9];
#pragma unroll
  for (int d = 0; d < 9; ++d) {
    int tt = t + d - 4;
    xv[d] = (tt >= 0 && tt < T_IN) ? xb[tt] : 0.f;
  }
  float y1[5][4];
#pragma unroll
  for (int u = 0; u < 5; ++u) {
    int tau = t + u - 2;
    bool valid = (tau >= 0 && tau < T_IN);
#pragma unroll
    for (int co = 0; co < 4; ++co) {
      float a = sb1[co];
#pragma unroll
      for (int k = 0; k < 5; ++k) a = fmaf(xv[u + k], sw1[k * 4 + co], a);
      y1[u][co] = valid ? (a / (1.f + expf(-a))) : 0.f;
    }
  }
  f16x8 o0, o1;
#pragma unroll
  for (int co = 0; co < 16; ++co) {
    float a = sb2[co];
#pragma unroll
    for (int u = 0; u < 5; ++u)
#pragma unroll
      for (int ci = 0; ci < 4; ++ci)
        a = fmaf(y1[u][ci], sw2[(u * 4 + ci) * 16 + co], a);
    float sv = a / (1.f + expf(-a));
    if (co < 8) o0[co] = (f16)sv; else o1[co - 8] = (f16)sv;
  }
  f16x8* dst = (f16x8*)(y2 + (size_t)flat * 16);
  dst[0] = o0;
  dst[1] = o1;
}

// ---------------------------------------------------------------------------
// conv3: (19,16,384), stride 5, SAME (pad 7/7), + silu. fp16 in/out, fp32 math.
// ---------------------------------------------------------------------------
__global__ __launch_bounds__(384) void conv3_kernel(
    const f16* __restrict__ y2, const float* __restrict__ w3, const float* __restrict__ b3,
    f16* __restrict__ act) {
  __shared__ float in_s[94 * 16];
  int tid = threadIdx.x;
  int b = blockIdx.y;
  int t0 = blockIdx.x * 16;
  int base_t = t0 * 5 - 7;
  for (int i = tid; i < 94 * 16; i += 384) {
    int tau = i >> 4, ci = i & 15;
    int tt = base_t + tau;
    in_s[i] = (tt >= 0 && tt < T_IN) ? (float)y2[((size_t)b * T_IN + tt) * 16 + ci] : 0.f;
  }
  __syncthreads();
  int c = tid;
  float acc[16];
  float bv = b3[c];
#pragma unroll
  for (int tt = 0; tt < 16; ++tt) acc[tt] = bv;
  for (int kk = 0; kk < 19; ++kk) {
#pragma unroll
    for (int c4 = 0; c4 < 4; ++c4) {
      float wa = w3[(size_t)((kk * 16 + c4 * 4 + 0) * 384) + c];
      float wb = w3[(size_t)((kk * 16 + c4 * 4 + 1) * 384) + c];
      float wc = w3[(size_t)((kk * 16 + c4 * 4 + 2) * 384) + c];
      float wd = w3[(size_t)((kk * 16 + c4 * 4 + 3) * 384) + c];
#pragma unroll
      for (int tt = 0; tt < 16; ++tt) {
        const float4 iv = *(const float4*)&in_s[(tt * 5 + kk) * 16 + c4 * 4];
        acc[tt] = fmaf(iv.x, wa, acc[tt]);
        acc[tt] = fmaf(iv.y, wb, acc[tt]);
        acc[tt] = fmaf(iv.z, wc, acc[tt]);
        acc[tt] = fmaf(iv.w, wd, acc[tt]);
      }
    }
  }
#pragma unroll
  for (int tt = 0; tt < 16; ++tt) {
    float a = acc[tt];
    a = a / (1.f + expf(-a));
    act[((size_t)b * T_OUT + t0 + tt) * HDIM + c] = (f16)a;
  }
}

// ---------------------------------------------------------------------------
// Chunked xg GEMM: xgc[b*TC+tl, :] = act[b, lo+tl, :] @ Wi (384x1536).
// act fp16, Wi fp32, xgc fp16; fp32 accumulate. 128x128 tile, 8x8 microtile.
// ---------------------------------------------------------------------------
__global__ __launch_bounds__(256) void gemm_xg_kernel(
    const f16* __restrict__ act, const float* __restrict__ Bw,
    f16* __restrict__ C, int lo) {
  __shared__ float As[16 * 132];
  __shared__ float Bs[16 * 128];
  int tid = threadIdx.x;
  int n0 = blockIdx.x * 128;
  int m0 = blockIdx.y * 128;
  int am = tid >> 2;
  int ak = (tid & 3) * 4;
  int bk = tid >> 5;
  int bn = (tid & 31) * 4;
  int row0 = m0 + am, row1 = row0 + 64;
  const f16* Ap0 = act + ((size_t)(row0 / TC) * T_OUT + lo + row0 % TC) * HDIM + ak;
  const f16* Ap1 = act + ((size_t)(row1 / TC) * T_OUT + lo + row1 % TC) * HDIM + ak;
  const float* Bp = Bw + (size_t)bk * GDIM + n0 + bn;
  f16x4 ra0 = *(const f16x4*)Ap0;
  f16x4 ra1 = *(const f16x4*)Ap1;
  float4 rb0 = *(const float4*)Bp;
  float4 rb1 = *(const float4*)(Bp + (size_t)8 * GDIM);
  float acc[8][8];
#pragma unroll
  for (int i = 0; i < 8; ++i)
#pragma unroll
    for (int j = 0; j < 8; ++j) acc[i][j] = 0.f;
  int tx = tid & 15, ty = tid >> 4;
  for (int kt = 0; kt < 24; ++kt) {
    As[(ak + 0) * 132 + am] = (float)ra0[0];
    As[(ak + 1) * 132 + am] = (float)ra0[1];
    As[(ak + 2) * 132 + am] = (float)ra0[2];
    As[(ak + 3) * 132 + am] = (float)ra0[3];
    As[(ak + 0) * 132 + am + 64] = (float)ra1[0];
    As[(ak + 1) * 132 + am + 64] = (float)ra1[1];
    As[(ak + 2) * 132 + am + 64] = (float)ra1[2];
    As[(ak + 3) * 132 + am + 64] = (float)ra1[3];
    *(float4*)&Bs[bk * 128 + bn] = rb0;
    *(float4*)&Bs[(bk + 8) * 128 + bn] = rb1;
    __syncthreads();
    if (kt < 23) {
      Ap0 += 16; Ap1 += 16; Bp += (size_t)16 * GDIM;
      ra0 = *(const f16x4*)Ap0;
      ra1 = *(const f16x4*)Ap1;
      rb0 = *(const float4*)Bp;
      rb1 = *(const float4*)(Bp + (size_t)8 * GDIM);
    }
#pragma unroll
    for (int k = 0; k < 16; ++k) {
      float4 a0 = *(const float4*)&As[k * 132 + ty * 4];
      float4 a1 = *(const float4*)&As[k * 132 + 64 + ty * 4];
      float4 b0 = *(const float4*)&Bs[k * 128 + tx * 4];
      float4 b1 = *(const float4*)&Bs[k * 128 + 64 + tx * 4];
      float av[8] = {a0.x, a0.y, a0.z, a0.w, a1.x, a1.y, a1.z, a1.w};
      float bv[8] = {b0.x, b0.y, b0.z, b0.w, b1.x, b1.y, b1.z, b1.w};
#pragma unroll
      for (int i = 0; i < 8; ++i)
#pragma unroll
        for (int j = 0; j < 8; ++j) acc[i][j] = fmaf(av[i], bv[j], acc[i][j]);
    }
    __syncthreads();
  }
#pragma unroll
  for (int i = 0; i < 8; ++i) {
    int mi = (i < 4) ? (ty * 4 + i) : (64 + ty * 4 + i - 4);
    f16* Cp = C + (size_t)(m0 + mi) * GDIM + n0;
    f16x4 p0, p1;
    p0[0] = (f16)acc[i][0]; p0[1] = (f16)acc[i][1]; p0[2] = (f16)acc[i][2]; p0[3] = (f16)acc[i][3];
    p1[0] = (f16)acc[i][4]; p1[1] = (f16)acc[i][5]; p1[2] = (f16)acc[i][6]; p1[3] = (f16)acc[i][7];
    *(f16x4*)(Cp + tx * 4) = p0;
    *(f16x4*)(Cp + 64 + tx * 4) = p1;
  }
}

// ---------------------------------------------------------------------------
__global__ void zero_ctr_kernel(int* __restrict__ ctr) {
  for (int i = threadIdx.x; i < 32 * CTR_STRIDE; i += 256) ctr[i] = 0;
}

// ---------------------------------------------------------------------------
// Chunked persistent LSTM recurrence. 256 blocks x 256 threads (1 block/CU by
// VGPR pressure -> co-resident). 32 groups x 8 WGs; group g owns batches
// 4g..4g+3; WG wg owns h-cols [48wg,48wg+48). ctr: one 128B line per group.
// Poll via fetch_add(0) RMW -> executes at coherence point, never stale.
// ---------------------------------------------------------------------------
__global__ __launch_bounds__(256, 1) void lstm_kernel(
    const f16* __restrict__ xg, const float* __restrict__ Wh,
    const float* __restrict__ bias, f16* __restrict__ act,
    float* __restrict__ c_state, int* __restrict__ ctr,
    int lo, int reverse, int first, int step_base) {
  int tid = threadIdx.x;
  int bid = blockIdx.x;
  int r8 = bid & 7, si = bid >> 3;
  int g = r8 * 4 + (si >> 3);   // 0..31
  int wg = si & 7;              // 0..7
  int bbase = g * 4;
  int jbase = wg * 48;
  int r = tid & 3, cg = tid >> 2;
  int* myctr = ctr + g * CTR_STRIDE;
  __shared__ float h_lds[4 * 400];   // [k-quarter r][batch b][100 pad]
  __shared__ float z_lds[4 * 200];   // [batch b][200 pad], col c = gate*48+j
  __shared__ float bias_s[192];
  float w[3][96];
  {
    int c0 = 3 * cg;
    int gate = c0 / 48;
    int j0 = c0 % 48;
    const float* whp = Wh + (size_t)(96 * r) * GDIM + gate * HDIM + jbase + j0;
#pragma unroll
    for (int k2 = 0; k2 < 96; ++k2) {
      const float* p = whp + (size_t)k2 * GDIM;
      w[0][k2] = p[0]; w[1][k2] = p[1]; w[2][k2] = p[2];
    }
  }
  if (tid < 192) bias_s[tid] = bias[(tid / 48) * HDIM + jbase + (tid % 48)];
  int hb = tid / 48, hj = tid % 48;  // valid for tid<192
  float c_st = 0.f;
  if (first) {
    for (int i = tid; i < 1600; i += 256) h_lds[i] = 0.f;
  } else {
    int tprev = reverse ? (lo + TC) : (lo - 1);
#pragma unroll
    for (int i = 0; i < 6; ++i) {
      int flat = i * 256 + tid;
      int bb = flat / 384, jj = flat % 384;
      unsigned short uu = __hip_atomic_load(
          (const unsigned short*)act + ((size_t)(bbase + bb) * T_OUT + tprev) * HDIM + jj,
          __ATOMIC_RELAXED, __HIP_MEMORY_SCOPE_AGENT);
      union { unsigned short u; f16 h; } cv; cv.u = uu;
      h_lds[(jj / 96) * 400 + bb * 100 + (jj % 96)] = (float)cv.h;
    }
    if (tid < 192) c_st = c_state[(size_t)(bbase + hb) * HDIM + jbase + hj];
  }
  __syncthreads();

  for (int s = 0; s < TC; ++s) {
    int t = reverse ? (lo + TC - 1 - s) : (lo + s);
    int tl = t - lo;
    float acc[3][4];
#pragma unroll
    for (int cc = 0; cc < 3; ++cc)
#pragma unroll
      for (int bb = 0; bb < 4; ++bb) acc[cc][bb] = 0.f;
#pragma unroll
    for (int kk = 0; kk < 96; kk += 4) {
      const float4 h0 = *(const float4*)&h_lds[r * 400 + 0   + kk];
      const float4 h1 = *(const float4*)&h_lds[r * 400 + 100 + kk];
      const float4 h2 = *(const float4*)&h_lds[r * 400 + 200 + kk];
      const float4 h3 = *(const float4*)&h_lds[r * 400 + 300 + kk];
#pragma unroll
      for (int cc = 0; cc < 3; ++cc) {
        const float w0 = w[cc][kk + 0], w1_ = w[cc][kk + 1];
        const float w2_ = w[cc][kk + 2], w3_ = w[cc][kk + 3];
        acc[cc][0] = fmaf(h0.x, w0, acc[cc][0]); acc[cc][0] = fmaf(h0.y, w1_, acc[cc][0]);
        acc[cc][0] = fmaf(h0.z, w2_, acc[cc][0]); acc[cc][0] = fmaf(h0.w, w3_, acc[cc][0]);
        acc[cc][1] = fmaf(h1.x, w0, acc[cc][1]); acc[cc][1] = fmaf(h1.y, w1_, acc[cc][1]);
        acc[cc][1] = fmaf(h1.z, w2_, acc[cc][1]); acc[cc][1] = fmaf(h1.w, w3_, acc[cc][1]);
        acc[cc][2] = fmaf(h2.x, w0, acc[cc][2]); acc[cc][2] = fmaf(h2.y, w1_, acc[cc][2]);
        acc[cc][2] = fmaf(h2.z, w2_, acc[cc][2]); acc[cc][2] = fmaf(h2.w, w3_, acc[cc][2]);
        acc[cc][3] = fmaf(h3.x, w0, acc[cc][3]); acc[cc][3] = fmaf(h3.y, w1_, acc[cc][3]);
        acc[cc][3] = fmaf(h3.z, w2_, acc[cc][3]); acc[cc][3] = fmaf(h3.w, w3_, acc[cc][3]);
      }
    }
#pragma unroll
    for (int cc = 0; cc < 3; ++cc)
#pragma unroll
      for (int bb = 0; bb < 4; ++bb) {
        float v = acc[cc][bb];
        v += __shfl_xor(v, 1);
        v += __shfl_xor(v, 2);
        acc[cc][bb] = v;
      }
    int c0 = 3 * cg;
    float z0 = (r == 0) ? acc[0][0] : (r == 1) ? acc[0][1] : (r == 2) ? acc[0][2] : acc[0][3];
    float z1 = (r == 0) ? acc[1][0] : (r == 1) ? acc[1][1] : (r == 2) ? acc[1][2] : acc[1][3];
    float z2 = (r == 0) ? acc[2][0] : (r == 1) ? acc[2][1] : (r == 2) ? acc[2][2] : acc[2][3];
    z_lds[r * 200 + c0 + 0] = z0;
    z_lds[r * 200 + c0 + 1] = z1;
    z_lds[r * 200 + c0 + 2] = z2;
    __syncthreads();
    if (tid < 192) {
      float zi = z_lds[hb * 200 + hj];
      float zf = z_lds[hb * 200 + 48 + hj];
      float zg = z_lds[hb * 200 + 96 + hj];
      float zo = z_lds[hb * 200 + 144 + hj];
      const f16* xp = xg + ((size_t)(bbase + hb) * TC + tl) * GDIM + jbase + hj;
      zi += (float)xp[0]    + bias_s[hj];
      zf += (float)xp[384]  + bias_s[48 + hj];
      zg += (float)xp[768]  + bias_s[96 + hj];
      zo += (float)xp[1152] + bias_s[144 + hj];
      float ig = 1.f / (1.f + expf(-zi));
      float fg = 1.f / (1.f + expf(-zf));
      float gv = tanhf(zg);
      float og = 1.f / (1.f + expf(-zo));
      c_st = fg * c_st + ig * gv;
      float hv = og * tanhf(c_st);
      union { unsigned short u; f16 h; } cv; cv.h = (f16)hv;
      __hip_atomic_store(
          (unsigned short*)act + ((size_t)(bbase + hb) * T_OUT + t) * HDIM + jbase + hj,
          cv.u, __ATOMIC_RELAXED, __HIP_MEMORY_SCOPE_AGENT);
    }
    __syncthreads();  // drains vmcnt -> h stores at coherence point
    if (tid == 0)
      __hip_atomic_fetch_add(myctr, 1, __ATOMIC_RELEASE, __HIP_MEMORY_SCOPE_AGENT);
    if (s + 1 < TC) {
      if (tid == 0) {
        int target = 8 * (step_base + s + 1);
        // RMW poll: always executes at the coherence point (never stale).
        int spins = 0;
        while (__hip_atomic_fetch_add(myctr, 0, __ATOMIC_RELAXED, __HIP_MEMORY_SCOPE_AGENT) < target &&
               spins < SPIN_MAX) {
          __builtin_amdgcn_s_sleep(16);
          ++spins;
        }
        (void)__hip_atomic_load(myctr, __ATOMIC_ACQUIRE, __HIP_MEMORY_SCOPE_AGENT);
      }
      __syncthreads();
#pragma unroll
      for (int i = 0; i < 6; ++i) {
        int flat = i * 256 + tid;
        int bb = flat / 384, jj = flat % 384;
        unsigned short uu = __hip_atomic_load(
            (const unsigned short*)act + ((size_t)(bbase + bb) * T_OUT + t) * HDIM + jj,
            __ATOMIC_RELAXED, __HIP_MEMORY_SCOPE_AGENT);
        union { unsigned short u; f16 h; } cv; cv.u = uu;
        h_lds[(jj / 96) * 400 + bb * 100 + (jj % 96)] = (float)cv.h;
      }
      __syncthreads();
    }
  }
  if (tid < 192) c_state[(size_t)(bbase + hb) * HDIM + jbase + hj] = c_st;
}

// ---------------------------------------------------------------------------
// dense: out(204800,5) = h(204800,384 fp16) @ W(384,5) + b  (fp32 out)
// ---------------------------------------------------------------------------
__global__ __launch_bounds__(256) void dense_kernel(
    const f16* __restrict__ h, const float* __restrict__ dw,
    const float* __restrict__ db, float* __restrict__ out) {
  __shared__ float ws_[1920];
  __shared__ float bs[5];
  int tid = threadIdx.x;
  for (int i = tid; i < 1920; i += 256) ws_[i] = dw[i];
  if (tid < 5) bs[tid] = db[tid];
  __syncthreads();
  size_t flat = (size_t)blockIdx.x * 256 + tid;
  const f16* hp = h + flat * HDIM;
  float acc[5];
#pragma unroll
  for (int o = 0; o < 5; ++o) acc[o] = bs[o];
  for (int d = 0; d < HDIM; d += 4) {
    f16x4 hv = *(const f16x4*)(hp + d);
#pragma unroll
    for (int o = 0; o < 5; ++o) {
      acc[o] = fmaf((float)hv[0], ws_[(d + 0) * 5 + o], acc[o]);
      acc[o] = fmaf((float)hv[1], ws_[(d + 1) * 5 + o], acc[o]);
      acc[o] = fmaf((float)hv[2], ws_[(d + 2) * 5 + o], acc[o]);
      acc[o] = fmaf((float)hv[3], ws_[(d + 3) * 5 + o], acc[o]);
    }
  }
  float* op = out + flat * 5;
#pragma unroll
  for (int o = 0; o < 5; ++o) op[o] = acc[o];
}

// ---------------------------------------------------------------------------
extern "C" void kernel_launch(void* const* d_in, const int* in_sizes, int n_in,
                              void* d_out, int out_size, void* d_ws, size_t ws_size,
                              hipStream_t stream) {
  const float* x  = (const float*)d_in[0];
  const float* w1 = (const float*)d_in[1];
  const float* b1 = (const float*)d_in[2];
  const float* w2 = (const float*)d_in[3];
  const float* b2 = (const float*)d_in[4];
  const float* w3 = (const float*)d_in[5];
  const float* b3 = (const float*)d_in[6];
  const float* Wi = (const float*)d_in[7];
  const float* Wh = (const float*)d_in[8];
  const float* lb = (const float*)d_in[9];
  const float* dw = (const float*)d_in[10];
  const float* db = (const float*)d_in[11];
  float* out = (float*)d_out;
  char* ws = (char*)d_ws;

  // ws layout (total ~197 MB): act fp16 | xgc fp16 | c_state fp32 | ctr
  const size_t ACT_BYTES = (size_t)B_SZ * T_OUT * HDIM * 2;   // 157.3 MB
  const size_t XGC_BYTES = (size_t)B_SZ * TC * GDIM * 2;      // 39.3 MB
  const size_t CST_BYTES = (size_t)B_SZ * HDIM * 4;           // 197 KB
  f16*   act = (f16*)ws;
  f16*   xgc = (f16*)(ws + ACT_BYTES);
  float* cst = (float*)(ws + ACT_BYTES + XGC_BYTES);
  int*   ctr = (int*)(ws + ACT_BYTES + XGC_BYTES + CST_BYTES);
  f16*   y2  = xgc;  // alias: conv12 out (32.8 MB) dead before first gemm

  hipLaunchKernelGGL(conv12_kernel, dim3(B_SZ * T_IN / 256), dim3(256), 0, stream,
                     x, w1, b1, w2, b2, y2);
  hipLaunchKernelGGL(conv3_kernel, dim3(T_OUT / 16, B_SZ), dim3(384), 0, stream,
                     y2, w3, b3, act);
  hipLaunchKernelGGL(zero_ctr_kernel, dim3(1), dim3(256), 0, stream, ctr);

  for (int l = 0; l < 5; ++l) {
    int rev = (l % 2 == 0) ? 1 : 0;
    const float* wi_p = Wi + (size_t)l * HDIM * GDIM;
    const float* wh_p = Wh + (size_t)l * HDIM * GDIM;
    const float* lb_p = lb + (size_t)l * GDIM;
    for (int ci = 0; ci < NCHUNK; ++ci) {
      int lo = rev ? (T_OUT - (ci + 1) * TC) : (ci * TC);
      hipLaunchKernelGGL(gemm_xg_kernel, dim3(GDIM / 128, (B_SZ * TC) / 128), dim3(256), 0, stream,
                         act, wi_p, xgc, lo);
      hipLaunchKernelGGL(lstm_kernel, dim3(256), dim3(256), 0, stream,
                         xgc, wh_p, lb_p, act, cst, ctr,
                         lo, rev, (ci == 0) ? 1 : 0, l * T_OUT + ci * TC);
    }
  }
  hipLaunchKernelGGL(dense_kernel, dim3((B_SZ * T_OUT) / 256), dim3(256), 0, stream,
                     act, dw, db, out);
}

// Round 6
// 157605.127 us; speedup vs baseline: 1.3473x; 1.1235x over previous
//
#include <hip/hip_runtime.h>
#include <math.h>

#define B_SZ 128
#define T_IN 8000
#define T_OUT 1600
#define HDIM 384
#define GDIM 1536   // 4*H
#define TC 80       // time chunk
#define NCHUNK (T_OUT / TC)   // 20

typedef _Float16 f16;
typedef __attribute__((ext_vector_type(2))) _Float16 f16x2;
typedef __attribute__((ext_vector_type(4))) _Float16 f16x4;
typedef __attribute__((ext_vector_type(8))) _Float16 f16x8;

__device__ inline float fdot2(f16x2 a, f16x2 b, float c) {
#if __has_builtin(__builtin_amdgcn_fdot2)
  return __builtin_amdgcn_fdot2(a, b, c, false);
#else
  return fmaf((float)a[0], (float)b[0], fmaf((float)a[1], (float)b[1], c));
#endif
}

// ---------------------------------------------------------------------------
// conv1 (5,1,4) + silu + conv2 (5,4,16) + silu, fused. One thread per (b,t).
// ---------------------------------------------------------------------------
__global__ __launch_bounds__(256) void conv12_kernel(
    const float* __restrict__ x, const float* __restrict__ w1, const float* __restrict__ b1,
    const float* __restrict__ w2, const float* __restrict__ b2, f16* __restrict__ y2) {
  __shared__ float sw1[20], sb1[4], sw2[320], sb2[16];
  int tid = threadIdx.x;
  if (tid < 20) sw1[tid] = w1[tid];
  if (tid < 4)  sb1[tid] = b1[tid];
  if (tid < 16) sb2[tid] = b2[tid];
  for (int i = tid; i < 320; i += 256) sw2[i] = w2[i];
  __syncthreads();
  int flat = blockIdx.x * 256 + tid;
  int b = flat / T_IN, t = flat % T_IN;
  const float* xb = x + (size_t)b * T_IN;
  float xv[9];
#pragma unroll
  for (int d = 0; d < 9; ++d) {
    int tt = t + d - 4;
    xv[d] = (tt >= 0 && tt < T_IN) ? xb[tt] : 0.f;
  }
  float y1[5][4];
#pragma unroll
  for (int u = 0; u < 5; ++u) {
    int tau = t + u - 2;
    bool valid = (tau >= 0 && tau < T_IN);
#pragma unroll
    for (int co = 0; co < 4; ++co) {
      float a = sb1[co];
#pragma unroll
      for (int k = 0; k < 5; ++k) a = fmaf(xv[u + k], sw1[k * 4 + co], a);
      y1[u][co] = valid ? (a / (1.f + expf(-a))) : 0.f;
    }
  }
  f16x8 o0, o1;
#pragma unroll
  for (int co = 0; co < 16; ++co) {
    float a = sb2[co];
#pragma unroll
    for (int u = 0; u < 5; ++u)
#pragma unroll
      for (int ci = 0; ci < 4; ++ci)
        a = fmaf(y1[u][ci], sw2[(u * 4 + ci) * 16 + co], a);
    float sv = a / (1.f + expf(-a));
    if (co < 8) o0[co] = (f16)sv; else o1[co - 8] = (f16)sv;
  }
  f16x8* dst = (f16x8*)(y2 + (size_t)flat * 16);
  dst[0] = o0;
  dst[1] = o1;
}

// ---------------------------------------------------------------------------
// conv3: (19,16,384), stride 5, SAME (pad 7/7), + silu. fp16 in/out, fp32 math.
// ---------------------------------------------------------------------------
__global__ __launch_bounds__(384) void conv3_kernel(
    const f16* __restrict__ y2, const float* __restrict__ w3, const float* __restrict__ b3,
    f16* __restrict__ act) {
  __shared__ float in_s[94 * 16];
  int tid = threadIdx.x;
  int b = blockIdx.y;
  int t0 = blockIdx.x * 16;
  int base_t = t0 * 5 - 7;
  for (int i = tid; i < 94 * 16; i += 384) {
    int tau = i >> 4, ci = i & 15;
    int tt = base_t + tau;
    in_s[i] = (tt >= 0 && tt < T_IN) ? (float)y2[((size_t)b * T_IN + tt) * 16 + ci] : 0.f;
  }
  __syncthreads();
  int c = tid;
  float acc[16];
  float bv = b3[c];
#pragma unroll
  for (int tt = 0; tt < 16; ++tt) acc[tt] = bv;
  for (int kk = 0; kk < 19; ++kk) {
#pragma unroll
    for (int c4 = 0; c4 < 4; ++c4) {
      float wa = w3[(size_t)((kk * 16 + c4 * 4 + 0) * 384) + c];
      float wb = w3[(size_t)((kk * 16 + c4 * 4 + 1) * 384) + c];
      float wc = w3[(size_t)((kk * 16 + c4 * 4 + 2) * 384) + c];
      float wd = w3[(size_t)((kk * 16 + c4 * 4 + 3) * 384) + c];
#pragma unroll
      for (int tt = 0; tt < 16; ++tt) {
        const float4 iv = *(const float4*)&in_s[(tt * 5 + kk) * 16 + c4 * 4];
        acc[tt] = fmaf(iv.x, wa, acc[tt]);
        acc[tt] = fmaf(iv.y, wb, acc[tt]);
        acc[tt] = fmaf(iv.z, wc, acc[tt]);
        acc[tt] = fmaf(iv.w, wd, acc[tt]);
      }
    }
  }
#pragma unroll
  for (int tt = 0; tt < 16; ++tt) {
    float a = acc[tt];
    a = a / (1.f + expf(-a));
    act[((size_t)b * T_OUT + t0 + tt) * HDIM + c] = (f16)a;
  }
}

// ---------------------------------------------------------------------------
// Wh repack: whP[l][k2][c] = (Wh[l][2k2][c], Wh[l][2k2+1][c]) as fp16x2.
// ---------------------------------------------------------------------------
__global__ __launch_bounds__(256) void whcvt_kernel(
    const float* __restrict__ Wh, f16x2* __restrict__ whP) {
  size_t idx = (size_t)blockIdx.x * 256 + threadIdx.x;   // < 5*192*1536
  int l = (int)(idx / (192 * 1536));
  int rem = (int)(idx % (192 * 1536));
  int k2 = rem / 1536;
  int c = rem % 1536;
  const float* src = Wh + ((size_t)l * 384 + 2 * k2) * 1536 + c;
  f16x2 v;
  v[0] = (f16)src[0];
  v[1] = (f16)src[1536];
  whP[idx] = v;
}

// ---------------------------------------------------------------------------
// Chunked xg GEMM: xgc[b*TC+tl, :] = act[b, lo+tl, :] @ Wi (384x1536).
// act fp16, Wi fp32, xgc fp16; fp32 accumulate. 128x128 tile, 8x8 microtile.
// ---------------------------------------------------------------------------
__global__ __launch_bounds__(256) void gemm_xg_kernel(
    const f16* __restrict__ act, const float* __restrict__ Bw,
    f16* __restrict__ C, int lo) {
  __shared__ float As[16 * 132];
  __shared__ float Bs[16 * 128];
  int tid = threadIdx.x;
  int n0 = blockIdx.x * 128;
  int m0 = blockIdx.y * 128;
  int am = tid >> 2;
  int ak = (tid & 3) * 4;
  int bk = tid >> 5;
  int bn = (tid & 31) * 4;
  int row0 = m0 + am, row1 = row0 + 64;
  const f16* Ap0 = act + ((size_t)(row0 / TC) * T_OUT + lo + row0 % TC) * HDIM + ak;
  const f16* Ap1 = act + ((size_t)(row1 / TC) * T_OUT + lo + row1 % TC) * HDIM + ak;
  const float* Bp = Bw + (size_t)bk * GDIM + n0 + bn;
  f16x4 ra0 = *(const f16x4*)Ap0;
  f16x4 ra1 = *(const f16x4*)Ap1;
  float4 rb0 = *(const float4*)Bp;
  float4 rb1 = *(const float4*)(Bp + (size_t)8 * GDIM);
  float acc[8][8];
#pragma unroll
  for (int i = 0; i < 8; ++i)
#pragma unroll
    for (int j = 0; j < 8; ++j) acc[i][j] = 0.f;
  int tx = tid & 15, ty = tid >> 4;
  for (int kt = 0; kt < 24; ++kt) {
    As[(ak + 0) * 132 + am] = (float)ra0[0];
    As[(ak + 1) * 132 + am] = (float)ra0[1];
    As[(ak + 2) * 132 + am] = (float)ra0[2];
    As[(ak + 3) * 132 + am] = (float)ra0[3];
    As[(ak + 0) * 132 + am + 64] = (float)ra1[0];
    As[(ak + 1) * 132 + am + 64] = (float)ra1[1];
    As[(ak + 2) * 132 + am + 64] = (float)ra1[2];
    As[(ak + 3) * 132 + am + 64] = (float)ra1[3];
    *(float4*)&Bs[bk * 128 + bn] = rb0;
    *(float4*)&Bs[(bk + 8) * 128 + bn] = rb1;
    __syncthreads();
    if (kt < 23) {
      Ap0 += 16; Ap1 += 16; Bp += (size_t)16 * GDIM;
      ra0 = *(const f16x4*)Ap0;
      ra1 = *(const f16x4*)Ap1;
      rb0 = *(const float4*)Bp;
      rb1 = *(const float4*)(Bp + (size_t)8 * GDIM);
    }
#pragma unroll
    for (int k = 0; k < 16; ++k) {
      float4 a0 = *(const float4*)&As[k * 132 + ty * 4];
      float4 a1 = *(const float4*)&As[k * 132 + 64 + ty * 4];
      float4 b0 = *(const float4*)&Bs[k * 128 + tx * 4];
      float4 b1 = *(const float4*)&Bs[k * 128 + 64 + tx * 4];
      float av[8] = {a0.x, a0.y, a0.z, a0.w, a1.x, a1.y, a1.z, a1.w};
      float bv[8] = {b0.x, b0.y, b0.z, b0.w, b1.x, b1.y, b1.z, b1.w};
#pragma unroll
      for (int i = 0; i < 8; ++i)
#pragma unroll
        for (int j = 0; j < 8; ++j) acc[i][j] = fmaf(av[i], bv[j], acc[i][j]);
    }
    __syncthreads();
  }
#pragma unroll
  for (int i = 0; i < 8; ++i) {
    int mi = (i < 4) ? (ty * 4 + i) : (64 + ty * 4 + i - 4);
    f16* Cp = C + (size_t)(m0 + mi) * GDIM + n0;
    f16x4 p0, p1;
    p0[0] = (f16)acc[i][0]; p0[1] = (f16)acc[i][1]; p0[2] = (f16)acc[i][2]; p0[3] = (f16)acc[i][3];
    p1[0] = (f16)acc[i][4]; p1[1] = (f16)acc[i][5]; p1[2] = (f16)acc[i][6]; p1[3] = (f16)acc[i][7];
    *(f16x4*)(Cp + tx * 4) = p0;
    *(f16x4*)(Cp + 64 + tx * 4) = p1;
  }
}

// ---------------------------------------------------------------------------
// LSTM recurrence, NO cross-WG sync. 64 WGs x 768 threads; WG w owns batches
// {2w, 2w+1}, ALL 384 h-columns. Wh (fp16-pair packed) streams from XCD L2
// every step; h lives in LDS; the only sync is __syncthreads.
// Thread map (both phases): bl = tid/384 (batch), j = tid%384.
// Phase A: z[bl][4j..4j+3] = sum_k Wh[k][c]*h[bl][k]  (768 fdot2/thread)
// Phase B: gates for (bl, j): c = j, 384+j, 768+j, 1152+j.
// ---------------------------------------------------------------------------
__global__ __launch_bounds__(768, 1) void lstm64_kernel(
    const f16* __restrict__ xgc, const f16x2* __restrict__ whP,
    const float* __restrict__ bias, f16* __restrict__ act,
    float* __restrict__ cst, int lo, int reverse, int first) {
  int tid = threadIdx.x;
  int wid = blockIdx.x;   // 0..63
  int b0 = wid * 2;
  __shared__ f16x2 h2s[2][192];
  __shared__ float zs[2][1536];
  __shared__ float bias_s[1536];
  for (int i = tid; i < 1536; i += 768) bias_s[i] = bias[i];
  int bl = tid / 384;
  int j = tid - bl * 384;
  float c_st;
  if (first) {
    c_st = 0.f;
    ((f16*)h2s)[tid] = (f16)0.f;
  } else {
    int tprev = reverse ? (lo + TC) : (lo - 1);
    c_st = cst[(size_t)(b0 + bl) * HDIM + j];
    ((f16*)&h2s[bl][0])[j] = act[((size_t)(b0 + bl) * T_OUT + tprev) * HDIM + j];
  }
  __syncthreads();

  int c4 = 4 * j;
  for (int s = 0; s < TC; ++s) {
    int t = reverse ? (lo + TC - 1 - s) : (lo + s);
    int tl = t - lo;
    // ---- phase A: Wh . h ----
    float a0 = 0.f, a1 = 0.f, a2 = 0.f, a3 = 0.f;
    const f16x8* hp8 = (const f16x8*)&h2s[bl][0];
    const f16x2* wp = whP + c4;
#pragma unroll 4
    for (int k8 = 0; k8 < 48; ++k8) {
      f16x8 hv8 = hp8[k8];   // LDS b128, wave-uniform -> broadcast
      f16x2 h0 = {hv8[0], hv8[1]}, h1 = {hv8[2], hv8[3]};
      f16x2 h2 = {hv8[4], hv8[5]}, h3 = {hv8[6], hv8[7]};
      f16x8 w0 = *(const f16x8*)(wp);
      f16x8 w1 = *(const f16x8*)(wp + 1536);
      f16x8 w2 = *(const f16x8*)(wp + 2 * 1536);
      f16x8 w3 = *(const f16x8*)(wp + 3 * 1536);
      a0 = fdot2((f16x2){w0[0], w0[1]}, h0, a0);
      a1 = fdot2((f16x2){w0[2], w0[3]}, h0, a1);
      a2 = fdot2((f16x2){w0[4], w0[5]}, h0, a2);
      a3 = fdot2((f16x2){w0[6], w0[7]}, h0, a3);
      a0 = fdot2((f16x2){w1[0], w1[1]}, h1, a0);
      a1 = fdot2((f16x2){w1[2], w1[3]}, h1, a1);
      a2 = fdot2((f16x2){w1[4], w1[5]}, h1, a2);
      a3 = fdot2((f16x2){w1[6], w1[7]}, h1, a3);
      a0 = fdot2((f16x2){w2[0], w2[1]}, h2, a0);
      a1 = fdot2((f16x2){w2[2], w2[3]}, h2, a1);
      a2 = fdot2((f16x2){w2[4], w2[5]}, h2, a2);
      a3 = fdot2((f16x2){w2[6], w2[7]}, h2, a3);
      a0 = fdot2((f16x2){w3[0], w3[1]}, h3, a0);
      a1 = fdot2((f16x2){w3[2], w3[3]}, h3, a1);
      a2 = fdot2((f16x2){w3[4], w3[5]}, h3, a2);
      a3 = fdot2((f16x2){w3[6], w3[7]}, h3, a3);
      wp += 4 * 1536;
    }
    *(float4*)&zs[bl][c4] = make_float4(a0, a1, a2, a3);
    __syncthreads();
    // ---- phase B: gates ----
    {
      float zi = zs[bl][j] + bias_s[j];
      float zf = zs[bl][384 + j] + bias_s[384 + j];
      float zg = zs[bl][768 + j] + bias_s[768 + j];
      float zo = zs[bl][1152 + j] + bias_s[1152 + j];
      const f16* xp = xgc + ((size_t)(b0 + bl) * TC + tl) * GDIM + j;
      zi += (float)xp[0];
      zf += (float)xp[384];
      zg += (float)xp[768];
      zo += (float)xp[1152];
      float ig = 1.f / (1.f + expf(-zi));
      float fg = 1.f / (1.f + expf(-zf));
      float gv = tanhf(zg);
      float og = 1.f / (1.f + expf(-zo));
      c_st = fg * c_st + ig * gv;
      float hv = og * tanhf(c_st);
      f16 h16v = (f16)hv;
      ((f16*)&h2s[bl][0])[j] = h16v;
      act[((size_t)(b0 + bl) * T_OUT + t) * HDIM + j] = h16v;
    }
    __syncthreads();
  }
  cst[(size_t)(b0 + bl) * HDIM + j] = c_st;
}

// ---------------------------------------------------------------------------
// dense: out(204800,5) = h(204800,384 fp16) @ W(384,5) + b  (fp32 out)
// ---------------------------------------------------------------------------
__global__ __launch_bounds__(256) void dense_kernel(
    const f16* __restrict__ h, const float* __restrict__ dw,
    const float* __restrict__ db, float* __restrict__ out) {
  __shared__ float ws_[1920];
  __shared__ float bs[5];
  int tid = threadIdx.x;
  for (int i = tid; i < 1920; i += 256) ws_[i] = dw[i];
  if (tid < 5) bs[tid] = db[tid];
  __syncthreads();
  size_t flat = (size_t)blockIdx.x * 256 + tid;
  const f16* hp = h + flat * HDIM;
  float acc[5];
#pragma unroll
  for (int o = 0; o < 5; ++o) acc[o] = bs[o];
  for (int d = 0; d < HDIM; d += 4) {
    f16x4 hv = *(const f16x4*)(hp + d);
#pragma unroll
    for (int o = 0; o < 5; ++o) {
      acc[o] = fmaf((float)hv[0], ws_[(d + 0) * 5 + o], acc[o]);
      acc[o] = fmaf((float)hv[1], ws_[(d + 1) * 5 + o], acc[o]);
      acc[o] = fmaf((float)hv[2], ws_[(d + 2) * 5 + o], acc[o]);
      acc[o] = fmaf((float)hv[3], ws_[(d + 3) * 5 + o], acc[o]);
    }
  }
  float* op = out + flat * 5;
#pragma unroll
  for (int o = 0; o < 5; ++o) op[o] = acc[o];
}

// ---------------------------------------------------------------------------
extern "C" void kernel_launch(void* const* d_in, const int* in_sizes, int n_in,
                              void* d_out, int out_size, void* d_ws, size_t ws_size,
                              hipStream_t stream) {
  const float* x  = (const float*)d_in[0];
  const float* w1 = (const float*)d_in[1];
  const float* b1 = (const float*)d_in[2];
  const float* w2 = (const float*)d_in[3];
  const float* b2 = (const float*)d_in[4];
  const float* w3 = (const float*)d_in[5];
  const float* b3 = (const float*)d_in[6];
  const float* Wi = (const float*)d_in[7];
  const float* Wh = (const float*)d_in[8];
  const float* lb = (const float*)d_in[9];
  const float* dw = (const float*)d_in[10];
  const float* db = (const float*)d_in[11];
  float* out = (float*)d_out;
  char* ws = (char*)d_ws;

  // ws layout (~195 MB, <= proven 197): act | xgc | whP | cst
  const size_t ACT_BYTES = (size_t)B_SZ * T_OUT * HDIM * 2;   // 157.3 MB
  const size_t XGC_BYTES = (size_t)B_SZ * TC * GDIM * 2;      // 31.5 MB
  const size_t WHP_BYTES = (size_t)5 * 192 * 1536 * 4;        // 5.9 MB
  f16*   act = (f16*)ws;
  f16*   xgc = (f16*)(ws + ACT_BYTES);
  f16x2* whP = (f16x2*)(ws + ACT_BYTES + XGC_BYTES);
  float* cst = (float*)(ws + ACT_BYTES + XGC_BYTES + WHP_BYTES);
  // y2 (32.8 MB) aliases xgc (+ first 1.3 MB of whP); both dead regions:
  // conv12 -> conv3 consume y2 BEFORE whcvt writes whP / gemm writes xgc.
  f16* y2 = xgc;

  hipLaunchKernelGGL(conv12_kernel, dim3(B_SZ * T_IN / 256), dim3(256), 0, stream,
                     x, w1, b1, w2, b2, y2);
  hipLaunchKernelGGL(conv3_kernel, dim3(T_OUT / 16, B_SZ), dim3(384), 0, stream,
                     y2, w3, b3, act);
  hipLaunchKernelGGL(whcvt_kernel, dim3(5 * 192 * 1536 / 256), dim3(256), 0, stream,
                     Wh, whP);

  for (int l = 0; l < 5; ++l) {
    int rev = (l % 2 == 0) ? 1 : 0;
    const float* wi_p = Wi + (size_t)l * HDIM * GDIM;
    const f16x2* wh_p = whP + (size_t)l * 192 * 1536;
    const float* lb_p = lb + (size_t)l * GDIM;
    for (int ci = 0; ci < NCHUNK; ++ci) {
      int lo = rev ? (T_OUT - (ci + 1) * TC) : (ci * TC);
      hipLaunchKernelGGL(gemm_xg_kernel, dim3(GDIM / 128, (B_SZ * TC) / 128), dim3(256), 0, stream,
                         act, wi_p, xgc, lo);
      hipLaunchKernelGGL(lstm64_kernel, dim3(64), dim3(768), 0, stream,
                         xgc, wh_p, lb_p, act, cst, lo, rev, (ci == 0) ? 1 : 0);
    }
  }
  hipLaunchKernelGGL(dense_kernel, dim3((B_SZ * T_OUT) / 256), dim3(256), 0, stream,
                     act, dw, db, out);
}

// Round 7
// 147842.627 us; speedup vs baseline: 1.4363x; 1.0660x over previous
//
#include <hip/hip_runtime.h>
#include <math.h>

#define B_SZ 128
#define T_IN 8000
#define T_OUT 1600
#define HDIM 384
#define GDIM 1536   // 4*H
#define TC 80       // time chunk
#define NCHUNK (T_OUT / TC)   // 20

typedef _Float16 f16;
typedef __attribute__((ext_vector_type(2))) _Float16 f16x2;
typedef __attribute__((ext_vector_type(4))) _Float16 f16x4;
typedef __attribute__((ext_vector_type(8))) _Float16 f16x8;

__device__ inline float fdot2(f16x2 a, f16x2 b, float c) {
#if __has_builtin(__builtin_amdgcn_fdot2)
  return __builtin_amdgcn_fdot2(a, b, c, false);
#else
  return fmaf((float)a[0], (float)b[0], fmaf((float)a[1], (float)b[1], c));
#endif
}

// ---------------------------------------------------------------------------
// conv1 (5,1,4) + silu + conv2 (5,4,16) + silu, fused. One thread per (b,t).
// ---------------------------------------------------------------------------
__global__ __launch_bounds__(256) void conv12_kernel(
    const float* __restrict__ x, const float* __restrict__ w1, const float* __restrict__ b1,
    const float* __restrict__ w2, const float* __restrict__ b2, f16* __restrict__ y2) {
  __shared__ float sw1[20], sb1[4], sw2[320], sb2[16];
  int tid = threadIdx.x;
  if (tid < 20) sw1[tid] = w1[tid];
  if (tid < 4)  sb1[tid] = b1[tid];
  if (tid < 16) sb2[tid] = b2[tid];
  for (int i = tid; i < 320; i += 256) sw2[i] = w2[i];
  __syncthreads();
  int flat = blockIdx.x * 256 + tid;
  int b = flat / T_IN, t = flat % T_IN;
  const float* xb = x + (size_t)b * T_IN;
  float xv[9];
#pragma unroll
  for (int d = 0; d < 9; ++d) {
    int tt = t + d - 4;
    xv[d] = (tt >= 0 && tt < T_IN) ? xb[tt] : 0.f;
  }
  float y1[5][4];
#pragma unroll
  for (int u = 0; u < 5; ++u) {
    int tau = t + u - 2;
    bool valid = (tau >= 0 && tau < T_IN);
#pragma unroll
    for (int co = 0; co < 4; ++co) {
      float a = sb1[co];
#pragma unroll
      for (int k = 0; k < 5; ++k) a = fmaf(xv[u + k], sw1[k * 4 + co], a);
      y1[u][co] = valid ? (a / (1.f + expf(-a))) : 0.f;
    }
  }
  f16x8 o0, o1;
#pragma unroll
  for (int co = 0; co < 16; ++co) {
    float a = sb2[co];
#pragma unroll
    for (int u = 0; u < 5; ++u)
#pragma unroll
      for (int ci = 0; ci < 4; ++ci)
        a = fmaf(y1[u][ci], sw2[(u * 4 + ci) * 16 + co], a);
    float sv = a / (1.f + expf(-a));
    if (co < 8) o0[co] = (f16)sv; else o1[co - 8] = (f16)sv;
  }
  f16x8* dst = (f16x8*)(y2 + (size_t)flat * 16);
  dst[0] = o0;
  dst[1] = o1;
}

// ---------------------------------------------------------------------------
// conv3: (19,16,384), stride 5, SAME (pad 7/7), + silu. fp16 in/out, fp32 math.
// ---------------------------------------------------------------------------
__global__ __launch_bounds__(384) void conv3_kernel(
    const f16* __restrict__ y2, const float* __restrict__ w3, const float* __restrict__ b3,
    f16* __restrict__ act) {
  __shared__ float in_s[94 * 16];
  int tid = threadIdx.x;
  int b = blockIdx.y;
  int t0 = blockIdx.x * 16;
  int base_t = t0 * 5 - 7;
  for (int i = tid; i < 94 * 16; i += 384) {
    int tau = i >> 4, ci = i & 15;
    int tt = base_t + tau;
    in_s[i] = (tt >= 0 && tt < T_IN) ? (float)y2[((size_t)b * T_IN + tt) * 16 + ci] : 0.f;
  }
  __syncthreads();
  int c = tid;
  float acc[16];
  float bv = b3[c];
#pragma unroll
  for (int tt = 0; tt < 16; ++tt) acc[tt] = bv;
  for (int kk = 0; kk < 19; ++kk) {
#pragma unroll
    for (int c4 = 0; c4 < 4; ++c4) {
      float wa = w3[(size_t)((kk * 16 + c4 * 4 + 0) * 384) + c];
      float wb = w3[(size_t)((kk * 16 + c4 * 4 + 1) * 384) + c];
      float wc = w3[(size_t)((kk * 16 + c4 * 4 + 2) * 384) + c];
      float wd = w3[(size_t)((kk * 16 + c4 * 4 + 3) * 384) + c];
#pragma unroll
      for (int tt = 0; tt < 16; ++tt) {
        const float4 iv = *(const float4*)&in_s[(tt * 5 + kk) * 16 + c4 * 4];
        acc[tt] = fmaf(iv.x, wa, acc[tt]);
        acc[tt] = fmaf(iv.y, wb, acc[tt]);
        acc[tt] = fmaf(iv.z, wc, acc[tt]);
        acc[tt] = fmaf(iv.w, wd, acc[tt]);
      }
    }
  }
#pragma unroll
  for (int tt = 0; tt < 16; ++tt) {
    float a = acc[tt];
    a = a / (1.f + expf(-a));
    act[((size_t)b * T_OUT + t0 + tt) * HDIM + c] = (f16)a;
  }
}

// ---------------------------------------------------------------------------
// Wh repack: whP[l][k2][c] = (Wh[l][2k2][c], Wh[l][2k2+1][c]) as fp16x2.
// ---------------------------------------------------------------------------
__global__ __launch_bounds__(256) void whcvt_kernel(
    const float* __restrict__ Wh, f16x2* __restrict__ whP) {
  size_t idx = (size_t)blockIdx.x * 256 + threadIdx.x;   // < 5*192*1536
  int l = (int)(idx / (192 * 1536));
  int rem = (int)(idx % (192 * 1536));
  int k2 = rem / 1536;
  int c = rem % 1536;
  const float* src = Wh + ((size_t)l * 384 + 2 * k2) * 1536 + c;
  f16x2 v;
  v[0] = (f16)src[0];
  v[1] = (f16)src[1536];
  whP[idx] = v;
}

// ---------------------------------------------------------------------------
// Chunked xg GEMM: xgc[b*TC+tl, :] = act[b, lo+tl, :] @ Wi (384x1536).
// fp16 inputs in LDS (f16x2 k-pairs), v_dot2_f32_f16 inner, fp32 accumulate.
// 128x128 tile, 8x8 microtile.
// ---------------------------------------------------------------------------
__global__ __launch_bounds__(256) void gemm_xg_kernel(
    const f16* __restrict__ act, const float* __restrict__ Bw,
    f16* __restrict__ C, int lo) {
  __shared__ f16x2 As2[8 * 136];   // [k2][m], pad 136 keeps 16B alignment
  __shared__ f16x2 Bs2[8 * 128];   // [k2][n]
  int tid = threadIdx.x;
  int n0 = blockIdx.x * 128;
  int m0 = blockIdx.y * 128;
  int am = tid >> 2;
  int ak = (tid & 3) * 4;          // k offset 0,4,8,12
  int bk = tid >> 5;               // k2 row 0..7
  int bn = (tid & 31) * 4;
  int row0 = m0 + am, row1 = row0 + 64;
  const f16* Ap0 = act + ((size_t)(row0 / TC) * T_OUT + lo + row0 % TC) * HDIM + ak;
  const f16* Ap1 = act + ((size_t)(row1 / TC) * T_OUT + lo + row1 % TC) * HDIM + ak;
  const float* Bp = Bw + (size_t)(2 * bk) * GDIM + n0 + bn;
  f16x4 ra0 = *(const f16x4*)Ap0;
  f16x4 ra1 = *(const f16x4*)Ap1;
  float4 rb0 = *(const float4*)Bp;
  float4 rb1 = *(const float4*)(Bp + (size_t)GDIM);
  float acc[8][8];
#pragma unroll
  for (int i = 0; i < 8; ++i)
#pragma unroll
    for (int j = 0; j < 8; ++j) acc[i][j] = 0.f;
  int tx = tid & 15, ty = tid >> 4;
  for (int kt = 0; kt < 24; ++kt) {
    int ak2 = ak >> 1;
    As2[(ak2 + 0) * 136 + am] = (f16x2){ra0[0], ra0[1]};
    As2[(ak2 + 1) * 136 + am] = (f16x2){ra0[2], ra0[3]};
    As2[(ak2 + 0) * 136 + am + 64] = (f16x2){ra1[0], ra1[1]};
    As2[(ak2 + 1) * 136 + am + 64] = (f16x2){ra1[2], ra1[3]};
    Bs2[bk * 128 + bn + 0] = (f16x2){(f16)rb0.x, (f16)rb1.x};
    Bs2[bk * 128 + bn + 1] = (f16x2){(f16)rb0.y, (f16)rb1.y};
    Bs2[bk * 128 + bn + 2] = (f16x2){(f16)rb0.z, (f16)rb1.z};
    Bs2[bk * 128 + bn + 3] = (f16x2){(f16)rb0.w, (f16)rb1.w};
    __syncthreads();
    if (kt < 23) {
      Ap0 += 16; Ap1 += 16; Bp += (size_t)16 * GDIM;
      ra0 = *(const f16x4*)Ap0;
      ra1 = *(const f16x4*)Ap1;
      rb0 = *(const float4*)Bp;
      rb1 = *(const float4*)(Bp + (size_t)GDIM);
    }
#pragma unroll
    for (int k2 = 0; k2 < 8; ++k2) {
      f16x8 a0 = *(const f16x8*)&As2[k2 * 136 + ty * 4];
      f16x8 a1 = *(const f16x8*)&As2[k2 * 136 + 64 + ty * 4];
      f16x8 b0 = *(const f16x8*)&Bs2[k2 * 128 + tx * 4];
      f16x8 b1 = *(const f16x8*)&Bs2[k2 * 128 + 64 + tx * 4];
      f16x2 av[8], bv[8];
#pragma unroll
      for (int q = 0; q < 4; ++q) {
        av[q] = (f16x2){a0[2 * q], a0[2 * q + 1]};
        av[q + 4] = (f16x2){a1[2 * q], a1[2 * q + 1]};
        bv[q] = (f16x2){b0[2 * q], b0[2 * q + 1]};
        bv[q + 4] = (f16x2){b1[2 * q], b1[2 * q + 1]};
      }
#pragma unroll
      for (int i = 0; i < 8; ++i)
#pragma unroll
        for (int j = 0; j < 8; ++j) acc[i][j] = fdot2(av[i], bv[j], acc[i][j]);
    }
    __syncthreads();
  }
#pragma unroll
  for (int i = 0; i < 8; ++i) {
    int mi = (i < 4) ? (ty * 4 + i) : (64 + ty * 4 + i - 4);
    f16* Cp = C + (size_t)(m0 + mi) * GDIM + n0;
    f16x4 p0, p1;
    p0[0] = (f16)acc[i][0]; p0[1] = (f16)acc[i][1]; p0[2] = (f16)acc[i][2]; p0[3] = (f16)acc[i][3];
    p1[0] = (f16)acc[i][4]; p1[1] = (f16)acc[i][5]; p1[2] = (f16)acc[i][6]; p1[3] = (f16)acc[i][7];
    *(f16x4*)(Cp + tx * 4) = p0;
    *(f16x4*)(Cp + 64 + tx * 4) = p1;
  }
}

// ---------------------------------------------------------------------------
// LSTM recurrence, no cross-WG sync, deduped weight stream.
// 64 WGs x 768 threads; WG w owns batches {2w, 2w+1}, all 384 h-cols.
// Phase A: thread t owns gate-cols {2t, 2t+1}; ONE 8B weight load per k2
// serves BOTH batches (4 fdot2). Weight bytes/WG/step = 1.18 MB (was 2.36).
// Phase B: thread t -> (bl = t/384, j = t%384) computes gates, updates c,h.
// ---------------------------------------------------------------------------
__global__ __launch_bounds__(768, 1) void lstm64_kernel(
    const f16* __restrict__ xgc, const f16x2* __restrict__ whP,
    const float* __restrict__ bias, f16* __restrict__ act,
    float* __restrict__ cst, int lo, int reverse, int first) {
  int tid = threadIdx.x;
  int wid = blockIdx.x;   // 0..63
  int b0 = wid * 2;
  __shared__ f16x2 h2s[2][192];     // [batch][k2] h pairs
  __shared__ float zs[2][1536];
  __shared__ float bias_s[1536];
  for (int i = tid; i < 1536; i += 768) bias_s[i] = bias[i];
  int bl = tid / 384;
  int j = tid - bl * 384;
  float c_st;
  if (first) {
    c_st = 0.f;
    ((f16*)h2s)[tid] = (f16)0.f;   // 768 f16 total
  } else {
    int tprev = reverse ? (lo + TC) : (lo - 1);
    c_st = cst[(size_t)(b0 + bl) * HDIM + j];
    ((f16*)&h2s[bl][0])[j] = act[((size_t)(b0 + bl) * T_OUT + tprev) * HDIM + j];
  }
  __syncthreads();

  int c2 = 2 * tid;
  for (int s = 0; s < TC; ++s) {
    int t = reverse ? (lo + TC - 1 - s) : (lo + s);
    int tl = t - lo;
    // ---- phase A: z[b][c] = sum_k Wh[k][c] h[b][k], cols {c2,c2+1}, b in {0,1}
    float a00 = 0.f, a01 = 0.f, a10 = 0.f, a11 = 0.f;
    const f16x2* wp = whP + c2;
#pragma unroll 8
    for (int k2 = 0; k2 < 192; ++k2) {
      f16x4 wv = *(const f16x4*)wp;      // cols c2,c2+1 at k-pair k2 (8B coalesced)
      f16x2 hb0 = h2s[0][k2];            // LDS broadcast
      f16x2 hb1 = h2s[1][k2];
      f16x2 w0 = {wv[0], wv[1]};
      f16x2 w1 = {wv[2], wv[3]};
      a00 = fdot2(w0, hb0, a00);
      a01 = fdot2(w1, hb0, a01);
      a10 = fdot2(w0, hb1, a10);
      a11 = fdot2(w1, hb1, a11);
      wp += 1536;
    }
    zs[0][c2] = a00; zs[0][c2 + 1] = a01;
    zs[1][c2] = a10; zs[1][c2 + 1] = a11;
    __syncthreads();
    // ---- phase B: gates ----
    {
      float zi = zs[bl][j] + bias_s[j];
      float zf = zs[bl][384 + j] + bias_s[384 + j];
      float zg = zs[bl][768 + j] + bias_s[768 + j];
      float zo = zs[bl][1152 + j] + bias_s[1152 + j];
      const f16* xp = xgc + ((size_t)(b0 + bl) * TC + tl) * GDIM + j;
      zi += (float)xp[0];
      zf += (float)xp[384];
      zg += (float)xp[768];
      zo += (float)xp[1152];
      float ig = 1.f / (1.f + expf(-zi));
      float fg = 1.f / (1.f + expf(-zf));
      float gv = tanhf(zg);
      float og = 1.f / (1.f + expf(-zo));
      c_st = fg * c_st + ig * gv;
      float hv = og * tanhf(c_st);
      f16 h16v = (f16)hv;
      ((f16*)&h2s[bl][0])[j] = h16v;
      act[((size_t)(b0 + bl) * T_OUT + t) * HDIM + j] = h16v;
    }
    __syncthreads();
  }
  cst[(size_t)(b0 + bl) * HDIM + j] = c_st;
}

// ---------------------------------------------------------------------------
// dense: out(204800,5) = h(204800,384 fp16) @ W(384,5) + b  (fp32 out)
// ---------------------------------------------------------------------------
__global__ __launch_bounds__(256) void dense_kernel(
    const f16* __restrict__ h, const float* __restrict__ dw,
    const float* __restrict__ db, float* __restrict__ out) {
  __shared__ float ws_[1920];
  __shared__ float bs[5];
  int tid = threadIdx.x;
  for (int i = tid; i < 1920; i += 256) ws_[i] = dw[i];
  if (tid < 5) bs[tid] = db[tid];
  __syncthreads();
  size_t flat = (size_t)blockIdx.x * 256 + tid;
  const f16* hp = h + flat * HDIM;
  float acc[5];
#pragma unroll
  for (int o = 0; o < 5; ++o) acc[o] = bs[o];
  for (int d = 0; d < HDIM; d += 4) {
    f16x4 hv = *(const f16x4*)(hp + d);
#pragma unroll
    for (int o = 0; o < 5; ++o) {
      acc[o] = fmaf((float)hv[0], ws_[(d + 0) * 5 + o], acc[o]);
      acc[o] = fmaf((float)hv[1], ws_[(d + 1) * 5 + o], acc[o]);
      acc[o] = fmaf((float)hv[2], ws_[(d + 2) * 5 + o], acc[o]);
      acc[o] = fmaf((float)hv[3], ws_[(d + 3) * 5 + o], acc[o]);
    }
  }
  float* op = out + flat * 5;
#pragma unroll
  for (int o = 0; o < 5; ++o) op[o] = acc[o];
}

// ---------------------------------------------------------------------------
extern "C" void kernel_launch(void* const* d_in, const int* in_sizes, int n_in,
                              void* d_out, int out_size, void* d_ws, size_t ws_size,
                              hipStream_t stream) {
  const float* x  = (const float*)d_in[0];
  const float* w1 = (const float*)d_in[1];
  const float* b1 = (const float*)d_in[2];
  const float* w2 = (const float*)d_in[3];
  const float* b2 = (const float*)d_in[4];
  const float* w3 = (const float*)d_in[5];
  const float* b3 = (const float*)d_in[6];
  const float* Wi = (const float*)d_in[7];
  const float* Wh = (const float*)d_in[8];
  const float* lb = (const float*)d_in[9];
  const float* dw = (const float*)d_in[10];
  const float* db = (const float*)d_in[11];
  float* out = (float*)d_out;
  char* ws = (char*)d_ws;

  // ws layout (~195 MB, <= proven 197): act | xgc | whP | cst
  const size_t ACT_BYTES = (size_t)B_SZ * T_OUT * HDIM * 2;   // 157.3 MB
  const size_t XGC_BYTES = (size_t)B_SZ * TC * GDIM * 2;      // 31.5 MB
  const size_t WHP_BYTES = (size_t)5 * 192 * 1536 * 4;        // 5.9 MB
  f16*   act = (f16*)ws;
  f16*   xgc = (f16*)(ws + ACT_BYTES);
  f16x2* whP = (f16x2*)(ws + ACT_BYTES + XGC_BYTES);
  float* cst = (float*)(ws + ACT_BYTES + XGC_BYTES + WHP_BYTES);
  // y2 (32.8 MB) aliases xgc+whP head; dead before whcvt/gemm write there.
  f16* y2 = xgc;

  hipLaunchKernelGGL(conv12_kernel, dim3(B_SZ * T_IN / 256), dim3(256), 0, stream,
                     x, w1, b1, w2, b2, y2);
  hipLaunchKernelGGL(conv3_kernel, dim3(T_OUT / 16, B_SZ), dim3(384), 0, stream,
                     y2, w3, b3, act);
  hipLaunchKernelGGL(whcvt_kernel, dim3(5 * 192 * 1536 / 256), dim3(256), 0, stream,
                     Wh, whP);

  for (int l = 0; l < 5; ++l) {
    int rev = (l % 2 == 0) ? 1 : 0;
    const float* wi_p = Wi + (size_t)l * HDIM * GDIM;
    const f16x2* wh_p = whP + (size_t)l * 192 * 1536;
    const float* lb_p = lb + (size_t)l * GDIM;
    for (int ci = 0; ci < NCHUNK; ++ci) {
      int lo = rev ? (T_OUT - (ci + 1) * TC) : (ci * TC);
      hipLaunchKernelGGL(gemm_xg_kernel, dim3(GDIM / 128, (B_SZ * TC) / 128), dim3(256), 0, stream,
                         act, wi_p, xgc, lo);
      hipLaunchKernelGGL(lstm64_kernel, dim3(64), dim3(768), 0, stream,
                         xgc, wh_p, lb_p, act, cst, lo, rev, (ci == 0) ? 1 : 0);
    }
  }
  hipLaunchKernelGGL(dense_kernel, dim3((B_SZ * T_OUT) / 256), dim3(256), 0, stream,
                     act, dw, db, out);
}

// Round 8
// 88814.282 us; speedup vs baseline: 2.3908x; 1.6646x over previous
//
#include <hip/hip_runtime.h>
#include <math.h>

#define B_SZ 128
#define T_IN 8000
#define T_OUT 1600
#define HDIM 384
#define GDIM 1536   // 4*H
#define TC 80       // time chunk
#define NCHUNK (T_OUT / TC)   // 20

typedef _Float16 f16;
typedef __attribute__((ext_vector_type(2))) _Float16 f16x2;
typedef __attribute__((ext_vector_type(4))) _Float16 f16x4;
typedef __attribute__((ext_vector_type(8))) _Float16 f16x8;

__device__ inline float fdot2(f16x2 a, f16x2 b, float c) {
#if __has_builtin(__builtin_amdgcn_fdot2)
  return __builtin_amdgcn_fdot2(a, b, c, false);
#else
  return fmaf((float)a[0], (float)b[0], fmaf((float)a[1], (float)b[1], c));
#endif
}

// ---------------------------------------------------------------------------
// conv1 (5,1,4) + silu + conv2 (5,4,16) + silu, fused. One thread per (b,t).
// ---------------------------------------------------------------------------
__global__ __launch_bounds__(256) void conv12_kernel(
    const float* __restrict__ x, const float* __restrict__ w1, const float* __restrict__ b1,
    const float* __restrict__ w2, const float* __restrict__ b2, f16* __restrict__ y2) {
  __shared__ float sw1[20], sb1[4], sw2[320], sb2[16];
  int tid = threadIdx.x;
  if (tid < 20) sw1[tid] = w1[tid];
  if (tid < 4)  sb1[tid] = b1[tid];
  if (tid < 16) sb2[tid] = b2[tid];
  for (int i = tid; i < 320; i += 256) sw2[i] = w2[i];
  __syncthreads();
  int flat = blockIdx.x * 256 + tid;
  int b = flat / T_IN, t = flat % T_IN;
  const float* xb = x + (size_t)b * T_IN;
  float xv[9];
#pragma unroll
  for (int d = 0; d < 9; ++d) {
    int tt = t + d - 4;
    xv[d] = (tt >= 0 && tt < T_IN) ? xb[tt] : 0.f;
  }
  float y1[5][4];
#pragma unroll
  for (int u = 0; u < 5; ++u) {
    int tau = t + u - 2;
    bool valid = (tau >= 0 && tau < T_IN);
#pragma unroll
    for (int co = 0; co < 4; ++co) {
      float a = sb1[co];
#pragma unroll
      for (int k = 0; k < 5; ++k) a = fmaf(xv[u + k], sw1[k * 4 + co], a);
      y1[u][co] = valid ? (a / (1.f + expf(-a))) : 0.f;
    }
  }
  f16x8 o0, o1;
#pragma unroll
  for (int co = 0; co < 16; ++co) {
    float a = sb2[co];
#pragma unroll
    for (int u = 0; u < 5; ++u)
#pragma unroll
      for (int ci = 0; ci < 4; ++ci)
        a = fmaf(y1[u][ci], sw2[(u * 4 + ci) * 16 + co], a);
    float sv = a / (1.f + expf(-a));
    if (co < 8) o0[co] = (f16)sv; else o1[co - 8] = (f16)sv;
  }
  f16x8* dst = (f16x8*)(y2 + (size_t)flat * 16);
  dst[0] = o0;
  dst[1] = o1;
}

// ---------------------------------------------------------------------------
// conv3: (19,16,384), stride 5, SAME (pad 7/7), + silu. fp16 in/out, fp32 math.
// ---------------------------------------------------------------------------
__global__ __launch_bounds__(384) void conv3_kernel(
    const f16* __restrict__ y2, const float* __restrict__ w3, const float* __restrict__ b3,
    f16* __restrict__ act) {
  __shared__ float in_s[94 * 16];
  int tid = threadIdx.x;
  int b = blockIdx.y;
  int t0 = blockIdx.x * 16;
  int base_t = t0 * 5 - 7;
  for (int i = tid; i < 94 * 16; i += 384) {
    int tau = i >> 4, ci = i & 15;
    int tt = base_t + tau;
    in_s[i] = (tt >= 0 && tt < T_IN) ? (float)y2[((size_t)b * T_IN + tt) * 16 + ci] : 0.f;
  }
  __syncthreads();
  int c = tid;
  float acc[16];
  float bv = b3[c];
#pragma unroll
  for (int tt = 0; tt < 16; ++tt) acc[tt] = bv;
  for (int kk = 0; kk < 19; ++kk) {
#pragma unroll
    for (int c4 = 0; c4 < 4; ++c4) {
      float wa = w3[(size_t)((kk * 16 + c4 * 4 + 0) * 384) + c];
      float wb = w3[(size_t)((kk * 16 + c4 * 4 + 1) * 384) + c];
      float wc = w3[(size_t)((kk * 16 + c4 * 4 + 2) * 384) + c];
      float wd = w3[(size_t)((kk * 16 + c4 * 4 + 3) * 384) + c];
#pragma unroll
      for (int tt = 0; tt < 16; ++tt) {
        const float4 iv = *(const float4*)&in_s[(tt * 5 + kk) * 16 + c4 * 4];
        acc[tt] = fmaf(iv.x, wa, acc[tt]);
        acc[tt] = fmaf(iv.y, wb, acc[tt]);
        acc[tt] = fmaf(iv.z, wc, acc[tt]);
        acc[tt] = fmaf(iv.w, wd, acc[tt]);
      }
    }
  }
#pragma unroll
  for (int tt = 0; tt < 16; ++tt) {
    float a = acc[tt];
    a = a / (1.f + expf(-a));
    act[((size_t)b * T_OUT + t0 + tt) * HDIM + c] = (f16)a;
  }
}

// ---------------------------------------------------------------------------
// Wh repack: whP[l][k2][c] = (Wh[l][2k2][c], Wh[l][2k2+1][c]) as fp16x2.
// ---------------------------------------------------------------------------
__global__ __launch_bounds__(256) void whcvt_kernel(
    const float* __restrict__ Wh, f16x2* __restrict__ whP) {
  size_t idx = (size_t)blockIdx.x * 256 + threadIdx.x;   // < 5*192*1536
  int l = (int)(idx / (192 * 1536));
  int rem = (int)(idx % (192 * 1536));
  int k2 = rem / 1536;
  int c = rem % 1536;
  const float* src = Wh + ((size_t)l * 384 + 2 * k2) * 1536 + c;
  f16x2 v;
  v[0] = (f16)src[0];
  v[1] = (f16)src[1536];
  whP[idx] = v;
}

// ---------------------------------------------------------------------------
// Chunked xg GEMM: xgc[b*TC+tl, :] = act[b, lo+tl, :] @ Wi (384x1536).
// fp16 inputs in LDS (f16x2 k-pairs), v_dot2_f32_f16 inner, fp32 accumulate.
// ---------------------------------------------------------------------------
__global__ __launch_bounds__(256) void gemm_xg_kernel(
    const f16* __restrict__ act, const float* __restrict__ Bw,
    f16* __restrict__ C, int lo) {
  __shared__ f16x2 As2[8 * 136];
  __shared__ f16x2 Bs2[8 * 128];
  int tid = threadIdx.x;
  int n0 = blockIdx.x * 128;
  int m0 = blockIdx.y * 128;
  int am = tid >> 2;
  int ak = (tid & 3) * 4;
  int bk = tid >> 5;
  int bn = (tid & 31) * 4;
  int row0 = m0 + am, row1 = row0 + 64;
  const f16* Ap0 = act + ((size_t)(row0 / TC) * T_OUT + lo + row0 % TC) * HDIM + ak;
  const f16* Ap1 = act + ((size_t)(row1 / TC) * T_OUT + lo + row1 % TC) * HDIM + ak;
  const float* Bp = Bw + (size_t)(2 * bk) * GDIM + n0 + bn;
  f16x4 ra0 = *(const f16x4*)Ap0;
  f16x4 ra1 = *(const f16x4*)Ap1;
  float4 rb0 = *(const float4*)Bp;
  float4 rb1 = *(const float4*)(Bp + (size_t)GDIM);
  float acc[8][8];
#pragma unroll
  for (int i = 0; i < 8; ++i)
#pragma unroll
    for (int j = 0; j < 8; ++j) acc[i][j] = 0.f;
  int tx = tid & 15, ty = tid >> 4;
  for (int kt = 0; kt < 24; ++kt) {
    int ak2 = ak >> 1;
    As2[(ak2 + 0) * 136 + am] = (f16x2){ra0[0], ra0[1]};
    As2[(ak2 + 1) * 136 + am] = (f16x2){ra0[2], ra0[3]};
    As2[(ak2 + 0) * 136 + am + 64] = (f16x2){ra1[0], ra1[1]};
    As2[(ak2 + 1) * 136 + am + 64] = (f16x2){ra1[2], ra1[3]};
    Bs2[bk * 128 + bn + 0] = (f16x2){(f16)rb0.x, (f16)rb1.x};
    Bs2[bk * 128 + bn + 1] = (f16x2){(f16)rb0.y, (f16)rb1.y};
    Bs2[bk * 128 + bn + 2] = (f16x2){(f16)rb0.z, (f16)rb1.z};
    Bs2[bk * 128 + bn + 3] = (f16x2){(f16)rb0.w, (f16)rb1.w};
    __syncthreads();
    if (kt < 23) {
      Ap0 += 16; Ap1 += 16; Bp += (size_t)16 * GDIM;
      ra0 = *(const f16x4*)Ap0;
      ra1 = *(const f16x4*)Ap1;
      rb0 = *(const float4*)Bp;
      rb1 = *(const float4*)(Bp + (size_t)GDIM);
    }
#pragma unroll
    for (int k2 = 0; k2 < 8; ++k2) {
      f16x8 a0 = *(const f16x8*)&As2[k2 * 136 + ty * 4];
      f16x8 a1 = *(const f16x8*)&As2[k2 * 136 + 64 + ty * 4];
      f16x8 b0 = *(const f16x8*)&Bs2[k2 * 128 + tx * 4];
      f16x8 b1 = *(const f16x8*)&Bs2[k2 * 128 + 64 + tx * 4];
      f16x2 av[8], bv[8];
#pragma unroll
      for (int q = 0; q < 4; ++q) {
        av[q] = (f16x2){a0[2 * q], a0[2 * q + 1]};
        av[q + 4] = (f16x2){a1[2 * q], a1[2 * q + 1]};
        bv[q] = (f16x2){b0[2 * q], b0[2 * q + 1]};
        bv[q + 4] = (f16x2){b1[2 * q], b1[2 * q + 1]};
      }
#pragma unroll
      for (int i = 0; i < 8; ++i)
#pragma unroll
        for (int j = 0; j < 8; ++j) acc[i][j] = fdot2(av[i], bv[j], acc[i][j]);
    }
    __syncthreads();
  }
#pragma unroll
  for (int i = 0; i < 8; ++i) {
    int mi = (i < 4) ? (ty * 4 + i) : (64 + ty * 4 + i - 4);
    f16* Cp = C + (size_t)(m0 + mi) * GDIM + n0;
    f16x4 p0, p1;
    p0[0] = (f16)acc[i][0]; p0[1] = (f16)acc[i][1]; p0[2] = (f16)acc[i][2]; p0[3] = (f16)acc[i][3];
    p1[0] = (f16)acc[i][4]; p1[1] = (f16)acc[i][5]; p1[2] = (f16)acc[i][6]; p1[3] = (f16)acc[i][7];
    *(f16x4*)(Cp + tx * 4) = p0;
    *(f16x4*)(Cp + 64 + tx * 4) = p1;
  }
}

// ---------------------------------------------------------------------------
// LSTM recurrence, no cross-WG sync, high-ILP phase A.
// 64 WGs x 768 threads; WG w owns batches {2w, 2w+1}, all 384 h-cols.
// Phase A map: kap = tid/384 (k-half), cq = tid%384 (col-quad).
//   Thread owns cols [4cq,4cq+4), k2 in [96kap, 96kap+96), BOTH batches:
//   8 fp32 accumulator chains, 96 x 16B weight loads, 48 x b128 h reads.
//   Partials to zsp[kap][b][c]; phase B sums the two k-halves.
// Phase B map: bl = tid/384, j = tid%384 -> gates, c/h update.
// ---------------------------------------------------------------------------
__global__ __launch_bounds__(768, 1) void lstm64_kernel(
    const f16* __restrict__ xgc, const f16x2* __restrict__ whP,
    const float* __restrict__ bias, f16* __restrict__ act,
    float* __restrict__ cst, int lo, int reverse, int first) {
  int tid = threadIdx.x;
  int wid = blockIdx.x;   // 0..63
  int b0 = wid * 2;
  __shared__ f16x2 h2s[2][192];        // [batch][k2] h pairs (1.5 KB)
  __shared__ float zsp[2][2][1536];    // [k-half][batch][col] partials (24 KB)
  __shared__ float bias_s[1536];       // 6 KB
  for (int i = tid; i < 1536; i += 768) bias_s[i] = bias[i];
  int bl = tid / 384;       // phase-B batch  (== kap in phase A)
  int j = tid - bl * 384;   // phase-B col    (== cq  in phase A)
  int kap = bl, cq = j;
  int c4 = 4 * cq;
  float c_st;
  if (first) {
    c_st = 0.f;
    ((f16*)h2s)[tid] = (f16)0.f;
  } else {
    int tprev = reverse ? (lo + TC) : (lo - 1);
    c_st = cst[(size_t)(b0 + bl) * HDIM + j];
    ((f16*)&h2s[bl][0])[j] = act[((size_t)(b0 + bl) * T_OUT + tprev) * HDIM + j];
  }
  __syncthreads();

  const f16x2* wcol = whP + c4 + (size_t)(96 * kap) * 1536;
  const int k2base = 96 * kap;

  for (int s = 0; s < TC; ++s) {
    int t = reverse ? (lo + TC - 1 - s) : (lo + s);
    int tl = t - lo;
    // ---- phase A: partial z for 4 cols x 2 batches over this k-half ----
    float a0[4] = {0.f, 0.f, 0.f, 0.f};
    float a1[4] = {0.f, 0.f, 0.f, 0.f};
    const f16x2* wp = wcol;
#pragma unroll 2
    for (int q = 0; q < 24; ++q) {
      int k2b = k2base + 4 * q;
      f16x8 w0 = *(const f16x8*)(wp);
      f16x8 w1 = *(const f16x8*)(wp + 1536);
      f16x8 w2 = *(const f16x8*)(wp + 2 * 1536);
      f16x8 w3 = *(const f16x8*)(wp + 3 * 1536);
      f16x8 ha = *(const f16x8*)&h2s[0][k2b];   // 4 k2-pairs, batch 0
      f16x8 hb = *(const f16x8*)&h2s[1][k2b];   // 4 k2-pairs, batch 1
      f16x2 ha0 = {ha[0], ha[1]}, ha1 = {ha[2], ha[3]}, ha2 = {ha[4], ha[5]}, ha3 = {ha[6], ha[7]};
      f16x2 hb0 = {hb[0], hb[1]}, hb1 = {hb[2], hb[3]}, hb2 = {hb[4], hb[5]}, hb3 = {hb[6], hb[7]};
#pragma unroll
      for (int c = 0; c < 4; ++c) {
        f16x2 wc0 = {w0[2 * c], w0[2 * c + 1]};
        f16x2 wc1 = {w1[2 * c], w1[2 * c + 1]};
        f16x2 wc2 = {w2[2 * c], w2[2 * c + 1]};
        f16x2 wc3 = {w3[2 * c], w3[2 * c + 1]};
        a0[c] = fdot2(wc0, ha0, a0[c]);
        a1[c] = fdot2(wc0, hb0, a1[c]);
        a0[c] = fdot2(wc1, ha1, a0[c]);
        a1[c] = fdot2(wc1, hb1, a1[c]);
        a0[c] = fdot2(wc2, ha2, a0[c]);
        a1[c] = fdot2(wc2, hb2, a1[c]);
        a0[c] = fdot2(wc3, ha3, a0[c]);
        a1[c] = fdot2(wc3, hb3, a1[c]);
      }
      wp += 4 * 1536;
    }
    *(float4*)&zsp[kap][0][c4] = make_float4(a0[0], a0[1], a0[2], a0[3]);
    *(float4*)&zsp[kap][1][c4] = make_float4(a1[0], a1[1], a1[2], a1[3]);
    __syncthreads();
    // ---- phase B: gates ----
    {
      float zi = zsp[0][bl][j]        + zsp[1][bl][j]        + bias_s[j];
      float zf = zsp[0][bl][384 + j]  + zsp[1][bl][384 + j]  + bias_s[384 + j];
      float zg = zsp[0][bl][768 + j]  + zsp[1][bl][768 + j]  + bias_s[768 + j];
      float zo = zsp[0][bl][1152 + j] + zsp[1][bl][1152 + j] + bias_s[1152 + j];
      const f16* xp = xgc + ((size_t)(b0 + bl) * TC + tl) * GDIM + j;
      zi += (float)xp[0];
      zf += (float)xp[384];
      zg += (float)xp[768];
      zo += (float)xp[1152];
      float ig = 1.f / (1.f + expf(-zi));
      float fg = 1.f / (1.f + expf(-zf));
      float gv = tanhf(zg);
      float og = 1.f / (1.f + expf(-zo));
      c_st = fg * c_st + ig * gv;
      float hv = og * tanhf(c_st);
      f16 h16v = (f16)hv;
      ((f16*)&h2s[bl][0])[j] = h16v;
      act[((size_t)(b0 + bl) * T_OUT + t) * HDIM + j] = h16v;
    }
    __syncthreads();
  }
  cst[(size_t)(b0 + bl) * HDIM + j] = c_st;
}

// ---------------------------------------------------------------------------
// dense: out(204800,5) = h(204800,384 fp16) @ W(384,5) + b  (fp32 out)
// ---------------------------------------------------------------------------
__global__ __launch_bounds__(256) void dense_kernel(
    const f16* __restrict__ h, const float* __restrict__ dw,
    const float* __restrict__ db, float* __restrict__ out) {
  __shared__ float ws_[1920];
  __shared__ float bs[5];
  int tid = threadIdx.x;
  for (int i = tid; i < 1920; i += 256) ws_[i] = dw[i];
  if (tid < 5) bs[tid] = db[tid];
  __syncthreads();
  size_t flat = (size_t)blockIdx.x * 256 + tid;
  const f16* hp = h + flat * HDIM;
  float acc[5];
#pragma unroll
  for (int o = 0; o < 5; ++o) acc[o] = bs[o];
  for (int d = 0; d < HDIM; d += 4) {
    f16x4 hv = *(const f16x4*)(hp + d);
#pragma unroll
    for (int o = 0; o < 5; ++o) {
      acc[o] = fmaf((float)hv[0], ws_[(d + 0) * 5 + o], acc[o]);
      acc[o] = fmaf((float)hv[1], ws_[(d + 1) * 5 + o], acc[o]);
      acc[o] = fmaf((float)hv[2], ws_[(d + 2) * 5 + o], acc[o]);
      acc[o] = fmaf((float)hv[3], ws_[(d + 3) * 5 + o], acc[o]);
    }
  }
  float* op = out + flat * 5;
#pragma unroll
  for (int o = 0; o < 5; ++o) op[o] = acc[o];
}

// ---------------------------------------------------------------------------
extern "C" void kernel_launch(void* const* d_in, const int* in_sizes, int n_in,
                              void* d_out, int out_size, void* d_ws, size_t ws_size,
                              hipStream_t stream) {
  const float* x  = (const float*)d_in[0];
  const float* w1 = (const float*)d_in[1];
  const float* b1 = (const float*)d_in[2];
  const float* w2 = (const float*)d_in[3];
  const float* b2 = (const float*)d_in[4];
  const float* w3 = (const float*)d_in[5];
  const float* b3 = (const float*)d_in[6];
  const float* Wi = (const float*)d_in[7];
  const float* Wh = (const float*)d_in[8];
  const float* lb = (const float*)d_in[9];
  const float* dw = (const float*)d_in[10];
  const float* db = (const float*)d_in[11];
  float* out = (float*)d_out;
  char* ws = (char*)d_ws;

  // ws layout (~195 MB, <= proven 197): act | xgc | whP | cst
  const size_t ACT_BYTES = (size_t)B_SZ * T_OUT * HDIM * 2;   // 157.3 MB
  const size_t XGC_BYTES = (size_t)B_SZ * TC * GDIM * 2;      // 31.5 MB
  const size_t WHP_BYTES = (size_t)5 * 192 * 1536 * 4;        // 5.9 MB
  f16*   act = (f16*)ws;
  f16*   xgc = (f16*)(ws + ACT_BYTES);
  f16x2* whP = (f16x2*)(ws + ACT_BYTES + XGC_BYTES);
  float* cst = (float*)(ws + ACT_BYTES + XGC_BYTES + WHP_BYTES);
  f16* y2 = xgc;  // alias: y2 dead before whcvt/gemm write there

  hipLaunchKernelGGL(conv12_kernel, dim3(B_SZ * T_IN / 256), dim3(256), 0, stream,
                     x, w1, b1, w2, b2, y2);
  hipLaunchKernelGGL(conv3_kernel, dim3(T_OUT / 16, B_SZ), dim3(384), 0, stream,
                     y2, w3, b3, act);
  hipLaunchKernelGGL(whcvt_kernel, dim3(5 * 192 * 1536 / 256), dim3(256), 0, stream,
                     Wh, whP);

  for (int l = 0; l < 5; ++l) {
    int rev = (l % 2 == 0) ? 1 : 0;
    const float* wi_p = Wi + (size_t)l * HDIM * GDIM;
    const f16x2* wh_p = whP + (size_t)l * 192 * 1536;
    const float* lb_p = lb + (size_t)l * GDIM;
    for (int ci = 0; ci < NCHUNK; ++ci) {
      int lo = rev ? (T_OUT - (ci + 1) * TC) : (ci * TC);
      hipLaunchKernelGGL(gemm_xg_kernel, dim3(GDIM / 128, (B_SZ * TC) / 128), dim3(256), 0, stream,
                         act, wi_p, xgc, lo);
      hipLaunchKernelGGL(lstm64_kernel, dim3(64), dim3(768), 0, stream,
                         xgc, wh_p, lb_p, act, cst, lo, rev, (ci == 0) ? 1 : 0);
    }
  }
  hipLaunchKernelGGL(dense_kernel, dim3((B_SZ * T_OUT) / 256), dim3(256), 0, stream,
                     act, dw, db, out);
}

// Round 9
// 79488.818 us; speedup vs baseline: 2.6713x; 1.1173x over previous
//
#include <hip/hip_runtime.h>
#include <math.h>

#define B_SZ 128
#define T_IN 8000
#define T_OUT 1600
#define HDIM 384
#define GDIM 1536   // 4*H
#define TC 40       // time chunk
#define NCHUNK (T_OUT / TC)   // 40
#define NTILES (12 * (B_SZ * TC / 128))   // 480 gemm tiles per chunk

typedef _Float16 f16;
typedef __attribute__((ext_vector_type(2))) _Float16 f16x2;
typedef __attribute__((ext_vector_type(4))) _Float16 f16x4;
typedef __attribute__((ext_vector_type(8))) _Float16 f16x8;

__device__ inline float fdot2(f16x2 a, f16x2 b, float c) {
#if __has_builtin(__builtin_amdgcn_fdot2)
  return __builtin_amdgcn_fdot2(a, b, c, false);
#else
  return fmaf((float)a[0], (float)b[0], fmaf((float)a[1], (float)b[1], c));
#endif
}

// ---------------------------------------------------------------------------
// conv1 (5,1,4) + silu + conv2 (5,4,16) + silu, fused. One thread per (b,t).
// ---------------------------------------------------------------------------
__global__ __launch_bounds__(256) void conv12_kernel(
    const float* __restrict__ x, const float* __restrict__ w1, const float* __restrict__ b1,
    const float* __restrict__ w2, const float* __restrict__ b2, f16* __restrict__ y2) {
  __shared__ float sw1[20], sb1[4], sw2[320], sb2[16];
  int tid = threadIdx.x;
  if (tid < 20) sw1[tid] = w1[tid];
  if (tid < 4)  sb1[tid] = b1[tid];
  if (tid < 16) sb2[tid] = b2[tid];
  for (int i = tid; i < 320; i += 256) sw2[i] = w2[i];
  __syncthreads();
  int flat = blockIdx.x * 256 + tid;
  int b = flat / T_IN, t = flat % T_IN;
  const float* xb = x + (size_t)b * T_IN;
  float xv[9];
#pragma unroll
  for (int d = 0; d < 9; ++d) {
    int tt = t + d - 4;
    xv[d] = (tt >= 0 && tt < T_IN) ? xb[tt] : 0.f;
  }
  float y1[5][4];
#pragma unroll
  for (int u = 0; u < 5; ++u) {
    int tau = t + u - 2;
    bool valid = (tau >= 0 && tau < T_IN);
#pragma unroll
    for (int co = 0; co < 4; ++co) {
      float a = sb1[co];
#pragma unroll
      for (int k = 0; k < 5; ++k) a = fmaf(xv[u + k], sw1[k * 4 + co], a);
      y1[u][co] = valid ? (a / (1.f + expf(-a))) : 0.f;
    }
  }
  f16x8 o0, o1;
#pragma unroll
  for (int co = 0; co < 16; ++co) {
    float a = sb2[co];
#pragma unroll
    for (int u = 0; u < 5; ++u)
#pragma unroll
      for (int ci = 0; ci < 4; ++ci)
        a = fmaf(y1[u][ci], sw2[(u * 4 + ci) * 16 + co], a);
    float sv = a / (1.f + expf(-a));
    if (co < 8) o0[co] = (f16)sv; else o1[co - 8] = (f16)sv;
  }
  f16x8* dst = (f16x8*)(y2 + (size_t)flat * 16);
  dst[0] = o0;
  dst[1] = o1;
}

// ---------------------------------------------------------------------------
// conv3: (19,16,384), stride 5, SAME (pad 7/7), + silu. fp16 in/out, fp32 math.
// ---------------------------------------------------------------------------
__global__ __launch_bounds__(384) void conv3_kernel(
    const f16* __restrict__ y2, const float* __restrict__ w3, const float* __restrict__ b3,
    f16* __restrict__ act) {
  __shared__ float in_s[94 * 16];
  int tid = threadIdx.x;
  int b = blockIdx.y;
  int t0 = blockIdx.x * 16;
  int base_t = t0 * 5 - 7;
  for (int i = tid; i < 94 * 16; i += 384) {
    int tau = i >> 4, ci = i & 15;
    int tt = base_t + tau;
    in_s[i] = (tt >= 0 && tt < T_IN) ? (float)y2[((size_t)b * T_IN + tt) * 16 + ci] : 0.f;
  }
  __syncthreads();
  int c = tid;
  float acc[16];
  float bv = b3[c];
#pragma unroll
  for (int tt = 0; tt < 16; ++tt) acc[tt] = bv;
  for (int kk = 0; kk < 19; ++kk) {
#pragma unroll
    for (int c4 = 0; c4 < 4; ++c4) {
      float wa = w3[(size_t)((kk * 16 + c4 * 4 + 0) * 384) + c];
      float wb = w3[(size_t)((kk * 16 + c4 * 4 + 1) * 384) + c];
      float wc = w3[(size_t)((kk * 16 + c4 * 4 + 2) * 384) + c];
      float wd = w3[(size_t)((kk * 16 + c4 * 4 + 3) * 384) + c];
#pragma unroll
      for (int tt = 0; tt < 16; ++tt) {
        const float4 iv = *(const float4*)&in_s[(tt * 5 + kk) * 16 + c4 * 4];
        acc[tt] = fmaf(iv.x, wa, acc[tt]);
        acc[tt] = fmaf(iv.y, wb, acc[tt]);
        acc[tt] = fmaf(iv.z, wc, acc[tt]);
        acc[tt] = fmaf(iv.w, wd, acc[tt]);
      }
    }
  }
#pragma unroll
  for (int tt = 0; tt < 16; ++tt) {
    float a = acc[tt];
    a = a / (1.f + expf(-a));
    act[((size_t)b * T_OUT + t0 + tt) * HDIM + c] = (f16)a;
  }
}

// ---------------------------------------------------------------------------
// Wh repack: whP[l][k2][c] = (Wh[l][2k2][c], Wh[l][2k2+1][c]) as fp16x2.
// ---------------------------------------------------------------------------
__global__ __launch_bounds__(256) void whcvt_kernel(
    const float* __restrict__ Wh, f16x2* __restrict__ whP) {
  size_t idx = (size_t)blockIdx.x * 256 + threadIdx.x;
  int l = (int)(idx / (192 * 1536));
  int rem = (int)(idx % (192 * 1536));
  int k2 = rem / 1536;
  int c = rem % 1536;
  const float* src = Wh + ((size_t)l * 384 + 2 * k2) * 1536 + c;
  f16x2 v;
  v[0] = (f16)src[0];
  v[1] = (f16)src[1536];
  whP[idx] = v;
}

// ---------------------------------------------------------------------------
// Standalone chunked xg GEMM (primes chunk 0 of each layer).
// ---------------------------------------------------------------------------
__global__ __launch_bounds__(256) void gemm_xg_kernel(
    const f16* __restrict__ act, const float* __restrict__ Bw,
    f16* __restrict__ C, int lo) {
  __shared__ f16x2 As2[8 * 136];
  __shared__ f16x2 Bs2[8 * 128];
  int tid = threadIdx.x;
  int n0 = blockIdx.x * 128;
  int m0 = blockIdx.y * 128;
  int am = tid >> 2;
  int ak = (tid & 3) * 4;
  int bk = tid >> 5;
  int bn = (tid & 31) * 4;
  int row0 = m0 + am, row1 = row0 + 64;
  const f16* Ap0 = act + ((size_t)(row0 / TC) * T_OUT + lo + row0 % TC) * HDIM + ak;
  const f16* Ap1 = act + ((size_t)(row1 / TC) * T_OUT + lo + row1 % TC) * HDIM + ak;
  const float* Bp = Bw + (size_t)(2 * bk) * GDIM + n0 + bn;
  f16x4 ra0 = *(const f16x4*)Ap0;
  f16x4 ra1 = *(const f16x4*)Ap1;
  float4 rb0 = *(const float4*)Bp;
  float4 rb1 = *(const float4*)(Bp + (size_t)GDIM);
  float acc[8][8];
#pragma unroll
  for (int i = 0; i < 8; ++i)
#pragma unroll
    for (int j = 0; j < 8; ++j) acc[i][j] = 0.f;
  int tx = tid & 15, ty = tid >> 4;
  for (int kt = 0; kt < 24; ++kt) {
    int ak2 = ak >> 1;
    As2[(ak2 + 0) * 136 + am] = (f16x2){ra0[0], ra0[1]};
    As2[(ak2 + 1) * 136 + am] = (f16x2){ra0[2], ra0[3]};
    As2[(ak2 + 0) * 136 + am + 64] = (f16x2){ra1[0], ra1[1]};
    As2[(ak2 + 1) * 136 + am + 64] = (f16x2){ra1[2], ra1[3]};
    Bs2[bk * 128 + bn + 0] = (f16x2){(f16)rb0.x, (f16)rb1.x};
    Bs2[bk * 128 + bn + 1] = (f16x2){(f16)rb0.y, (f16)rb1.y};
    Bs2[bk * 128 + bn + 2] = (f16x2){(f16)rb0.z, (f16)rb1.z};
    Bs2[bk * 128 + bn + 3] = (f16x2){(f16)rb0.w, (f16)rb1.w};
    __syncthreads();
    if (kt < 23) {
      Ap0 += 16; Ap1 += 16; Bp += (size_t)16 * GDIM;
      ra0 = *(const f16x4*)Ap0;
      ra1 = *(const f16x4*)Ap1;
      rb0 = *(const float4*)Bp;
      rb1 = *(const float4*)(Bp + (size_t)GDIM);
    }
#pragma unroll
    for (int k2 = 0; k2 < 8; ++k2) {
      f16x8 a0 = *(const f16x8*)&As2[k2 * 136 + ty * 4];
      f16x8 a1 = *(const f16x8*)&As2[k2 * 136 + 64 + ty * 4];
      f16x8 b0 = *(const f16x8*)&Bs2[k2 * 128 + tx * 4];
      f16x8 b1 = *(const f16x8*)&Bs2[k2 * 128 + 64 + tx * 4];
      f16x2 av[8], bv[8];
#pragma unroll
      for (int q = 0; q < 4; ++q) {
        av[q] = (f16x2){a0[2 * q], a0[2 * q + 1]};
        av[q + 4] = (f16x2){a1[2 * q], a1[2 * q + 1]};
        bv[q] = (f16x2){b0[2 * q], b0[2 * q + 1]};
        bv[q + 4] = (f16x2){b1[2 * q], b1[2 * q + 1]};
      }
#pragma unroll
      for (int i = 0; i < 8; ++i)
#pragma unroll
        for (int j = 0; j < 8; ++j) acc[i][j] = fdot2(av[i], bv[j], acc[i][j]);
    }
    __syncthreads();
  }
#pragma unroll
  for (int i = 0; i < 8; ++i) {
    int mi = (i < 4) ? (ty * 4 + i) : (64 + ty * 4 + i - 4);
    f16* Cp = C + (size_t)(m0 + mi) * GDIM + n0;
    f16x4 p0, p1;
    p0[0] = (f16)acc[i][0]; p0[1] = (f16)acc[i][1]; p0[2] = (f16)acc[i][2]; p0[3] = (f16)acc[i][3];
    p1[0] = (f16)acc[i][4]; p1[1] = (f16)acc[i][5]; p1[2] = (f16)acc[i][6]; p1[3] = (f16)acc[i][7];
    *(f16x4*)(Cp + tx * 4) = p0;
    *(f16x4*)(Cp + 64 + tx * 4) = p1;
  }
}

// ---------------------------------------------------------------------------
// FUSED kernel: 256 blocks x 768 threads.
//  blocks 0..63  : LSTM recurrence for chunk at lo_l (reads xgc_rd)
//  blocks 64..255: GEMM for next chunk at lo_g (writes xgc_wr); each block =
//                  3 independent 256-thread sub-tiles with uniform barriers.
// No inter-block communication -> correct under any scheduling.
// LDS padded to 56 KB -> at most 2 blocks/CU; 256 blocks ~ 1/CU.
// ---------------------------------------------------------------------------
union FusedSh {
  struct { f16x2 h2s[2][192]; float zsp[2][2][1536]; float bias_s[1536]; } L;
  struct { f16x2 As2[3][8 * 136]; f16x2 Bs2[3][8 * 128]; } G;
  char pad[57344];
};

__global__ __launch_bounds__(768, 1) void fused_kernel(
    const f16* __restrict__ xgc_rd, f16* __restrict__ xgc_wr,
    const f16x2* __restrict__ whP, const float* __restrict__ bias,
    f16* __restrict__ act, float* __restrict__ cst, const float* __restrict__ Wi,
    int lo_l, int lo_g, int reverse, int first, int do_gemm) {
  __shared__ FusedSh sh;
  int tid = threadIdx.x;

  if (blockIdx.x < 64) {
    // ================= LSTM branch =================
    int wid = blockIdx.x;
    int b0 = wid * 2;
    for (int i = tid; i < 1536; i += 768) sh.L.bias_s[i] = bias[i];
    int bl = tid / 384;
    int j = tid - bl * 384;
    int kap = bl, cq = j;
    int c4 = 4 * cq;
    float c_st;
    if (first) {
      c_st = 0.f;
      ((f16*)sh.L.h2s)[tid] = (f16)0.f;
    } else {
      int tprev = reverse ? (lo_l + TC) : (lo_l - 1);
      c_st = cst[(size_t)(b0 + bl) * HDIM + j];
      ((f16*)&sh.L.h2s[bl][0])[j] = act[((size_t)(b0 + bl) * T_OUT + tprev) * HDIM + j];
    }
    __syncthreads();

    const f16x2* wcol = whP + c4 + (size_t)(96 * kap) * 1536;
    const int k2base = 96 * kap;

    for (int s = 0; s < TC; ++s) {
      int t = reverse ? (lo_l + TC - 1 - s) : (lo_l + s);
      int tl = t - lo_l;
      float a0[4] = {0.f, 0.f, 0.f, 0.f};
      float a1[4] = {0.f, 0.f, 0.f, 0.f};
      const f16x2* wp = wcol;
#pragma unroll 2
      for (int q = 0; q < 24; ++q) {
        int k2b = k2base + 4 * q;
        f16x8 w0 = *(const f16x8*)(wp);
        f16x8 w1 = *(const f16x8*)(wp + 1536);
        f16x8 w2 = *(const f16x8*)(wp + 2 * 1536);
        f16x8 w3 = *(const f16x8*)(wp + 3 * 1536);
        f16x8 ha = *(const f16x8*)&sh.L.h2s[0][k2b];
        f16x8 hb = *(const f16x8*)&sh.L.h2s[1][k2b];
        f16x2 ha0 = {ha[0], ha[1]}, ha1 = {ha[2], ha[3]}, ha2 = {ha[4], ha[5]}, ha3 = {ha[6], ha[7]};
        f16x2 hb0 = {hb[0], hb[1]}, hb1 = {hb[2], hb[3]}, hb2 = {hb[4], hb[5]}, hb3 = {hb[6], hb[7]};
#pragma unroll
        for (int c = 0; c < 4; ++c) {
          f16x2 wc0 = {w0[2 * c], w0[2 * c + 1]};
          f16x2 wc1 = {w1[2 * c], w1[2 * c + 1]};
          f16x2 wc2 = {w2[2 * c], w2[2 * c + 1]};
          f16x2 wc3 = {w3[2 * c], w3[2 * c + 1]};
          a0[c] = fdot2(wc0, ha0, a0[c]);
          a1[c] = fdot2(wc0, hb0, a1[c]);
          a0[c] = fdot2(wc1, ha1, a0[c]);
          a1[c] = fdot2(wc1, hb1, a1[c]);
          a0[c] = fdot2(wc2, ha2, a0[c]);
          a1[c] = fdot2(wc2, hb2, a1[c]);
          a0[c] = fdot2(wc3, ha3, a0[c]);
          a1[c] = fdot2(wc3, hb3, a1[c]);
        }
        wp += 4 * 1536;
      }
      *(float4*)&sh.L.zsp[kap][0][c4] = make_float4(a0[0], a0[1], a0[2], a0[3]);
      *(float4*)&sh.L.zsp[kap][1][c4] = make_float4(a1[0], a1[1], a1[2], a1[3]);
      __syncthreads();
      {
        float zi = sh.L.zsp[0][bl][j]        + sh.L.zsp[1][bl][j]        + sh.L.bias_s[j];
        float zf = sh.L.zsp[0][bl][384 + j]  + sh.L.zsp[1][bl][384 + j]  + sh.L.bias_s[384 + j];
        float zg = sh.L.zsp[0][bl][768 + j]  + sh.L.zsp[1][bl][768 + j]  + sh.L.bias_s[768 + j];
        float zo = sh.L.zsp[0][bl][1152 + j] + sh.L.zsp[1][bl][1152 + j] + sh.L.bias_s[1152 + j];
        const f16* xp = xgc_rd + ((size_t)(b0 + bl) * TC + tl) * GDIM + j;
        zi += (float)xp[0];
        zf += (float)xp[384];
        zg += (float)xp[768];
        zo += (float)xp[1152];
        float ig = 1.f / (1.f + expf(-zi));
        float fg = 1.f / (1.f + expf(-zf));
        float gv = tanhf(zg);
        float og = 1.f / (1.f + expf(-zo));
        c_st = fg * c_st + ig * gv;
        float hv = og * tanhf(c_st);
        f16 h16v = (f16)hv;
        ((f16*)&sh.L.h2s[bl][0])[j] = h16v;
        act[((size_t)(b0 + bl) * T_OUT + t) * HDIM + j] = h16v;
      }
      __syncthreads();
    }
    cst[(size_t)(b0 + bl) * HDIM + j] = c_st;
  } else {
    // ================= GEMM worker branch =================
    if (!do_gemm) return;
    int wid = blockIdx.x - 64;        // 0..191
    int sub = tid >> 8;               // 0..2
    int stid = tid & 255;
    int tileid = wid + 192 * sub;     // 0..575
    bool valid = (tileid < NTILES);
    int tclamp = valid ? tileid : 0;
    int n0 = (tclamp % 12) * 128;
    int m0 = (tclamp / 12) * 128;
    f16x2* As2 = &sh.G.As2[sub][0];
    f16x2* Bs2 = &sh.G.Bs2[sub][0];
    int am = stid >> 2;
    int ak = (stid & 3) * 4;
    int bk = stid >> 5;
    int bn = (stid & 31) * 4;
    int row0 = m0 + am, row1 = row0 + 64;
    const f16* Ap0 = act + ((size_t)(row0 / TC) * T_OUT + lo_g + row0 % TC) * HDIM + ak;
    const f16* Ap1 = act + ((size_t)(row1 / TC) * T_OUT + lo_g + row1 % TC) * HDIM + ak;
    const float* Bp = Wi + (size_t)(2 * bk) * GDIM + n0 + bn;
    f16x4 ra0 = *(const f16x4*)Ap0;
    f16x4 ra1 = *(const f16x4*)Ap1;
    float4 rb0 = *(const float4*)Bp;
    float4 rb1 = *(const float4*)(Bp + (size_t)GDIM);
    float acc[8][8];
#pragma unroll
    for (int i = 0; i < 8; ++i)
#pragma unroll
      for (int j = 0; j < 8; ++j) acc[i][j] = 0.f;
    int tx = stid & 15, ty = stid >> 4;
    for (int kt = 0; kt < 24; ++kt) {
      int ak2 = ak >> 1;
      As2[(ak2 + 0) * 136 + am] = (f16x2){ra0[0], ra0[1]};
      As2[(ak2 + 1) * 136 + am] = (f16x2){ra0[2], ra0[3]};
      As2[(ak2 + 0) * 136 + am + 64] = (f16x2){ra1[0], ra1[1]};
      As2[(ak2 + 1) * 136 + am + 64] = (f16x2){ra1[2], ra1[3]};
      Bs2[bk * 128 + bn + 0] = (f16x2){(f16)rb0.x, (f16)rb1.x};
      Bs2[bk * 128 + bn + 1] = (f16x2){(f16)rb0.y, (f16)rb1.y};
      Bs2[bk * 128 + bn + 2] = (f16x2){(f16)rb0.z, (f16)rb1.z};
      Bs2[bk * 128 + bn + 3] = (f16x2){(f16)rb0.w, (f16)rb1.w};
      __syncthreads();
      if (kt < 23) {
        Ap0 += 16; Ap1 += 16; Bp += (size_t)16 * GDIM;
        ra0 = *(const f16x4*)Ap0;
        ra1 = *(const f16x4*)Ap1;
        rb0 = *(const float4*)Bp;
        rb1 = *(const float4*)(Bp + (size_t)GDIM);
      }
#pragma unroll
      for (int k2 = 0; k2 < 8; ++k2) {
        f16x8 a0 = *(const f16x8*)&As2[k2 * 136 + ty * 4];
        f16x8 a1 = *(const f16x8*)&As2[k2 * 136 + 64 + ty * 4];
        f16x8 b0 = *(const f16x8*)&Bs2[k2 * 128 + tx * 4];
        f16x8 b1 = *(const f16x8*)&Bs2[k2 * 128 + 64 + tx * 4];
        f16x2 av[8], bv[8];
#pragma unroll
        for (int q = 0; q < 4; ++q) {
          av[q] = (f16x2){a0[2 * q], a0[2 * q + 1]};
          av[q + 4] = (f16x2){a1[2 * q], a1[2 * q + 1]};
          bv[q] = (f16x2){b0[2 * q], b0[2 * q + 1]};
          bv[q + 4] = (f16x2){b1[2 * q], b1[2 * q + 1]};
        }
#pragma unroll
        for (int i = 0; i < 8; ++i)
#pragma unroll
          for (int j = 0; j < 8; ++j) acc[i][j] = fdot2(av[i], bv[j], acc[i][j]);
      }
      __syncthreads();
    }
    if (valid) {
#pragma unroll
      for (int i = 0; i < 8; ++i) {
        int mi = (i < 4) ? (ty * 4 + i) : (64 + ty * 4 + i - 4);
        f16* Cp = xgc_wr + (size_t)(m0 + mi) * GDIM + n0;
        f16x4 p0, p1;
        p0[0] = (f16)acc[i][0]; p0[1] = (f16)acc[i][1]; p0[2] = (f16)acc[i][2]; p0[3] = (f16)acc[i][3];
        p1[0] = (f16)acc[i][4]; p1[1] = (f16)acc[i][5]; p1[2] = (f16)acc[i][6]; p1[3] = (f16)acc[i][7];
        *(f16x4*)(Cp + tx * 4) = p0;
        *(f16x4*)(Cp + 64 + tx * 4) = p1;
      }
    }
  }
}

// ---------------------------------------------------------------------------
// dense: out(204800,5) = h(204800,384 fp16) @ W(384,5) + b  (fp32 out)
// ---------------------------------------------------------------------------
__global__ __launch_bounds__(256) void dense_kernel(
    const f16* __restrict__ h, const float* __restrict__ dw,
    const float* __restrict__ db, float* __restrict__ out) {
  __shared__ float ws_[1920];
  __shared__ float bs[5];
  int tid = threadIdx.x;
  for (int i = tid; i < 1920; i += 256) ws_[i] = dw[i];
  if (tid < 5) bs[tid] = db[tid];
  __syncthreads();
  size_t flat = (size_t)blockIdx.x * 256 + tid;
  const f16* hp = h + flat * HDIM;
  float acc[5];
#pragma unroll
  for (int o = 0; o < 5; ++o) acc[o] = bs[o];
  for (int d = 0; d < HDIM; d += 4) {
    f16x4 hv = *(const f16x4*)(hp + d);
#pragma unroll
    for (int o = 0; o < 5; ++o) {
      acc[o] = fmaf((float)hv[0], ws_[(d + 0) * 5 + o], acc[o]);
      acc[o] = fmaf((float)hv[1], ws_[(d + 1) * 5 + o], acc[o]);
      acc[o] = fmaf((float)hv[2], ws_[(d + 2) * 5 + o], acc[o]);
      acc[o] = fmaf((float)hv[3], ws_[(d + 3) * 5 + o], acc[o]);
    }
  }
  float* op = out + flat * 5;
#pragma unroll
  for (int o = 0; o < 5; ++o) op[o] = acc[o];
}

// ---------------------------------------------------------------------------
extern "C" void kernel_launch(void* const* d_in, const int* in_sizes, int n_in,
                              void* d_out, int out_size, void* d_ws, size_t ws_size,
                              hipStream_t stream) {
  const float* x  = (const float*)d_in[0];
  const float* w1 = (const float*)d_in[1];
  const float* b1 = (const float*)d_in[2];
  const float* w2 = (const float*)d_in[3];
  const float* b2 = (const float*)d_in[4];
  const float* w3 = (const float*)d_in[5];
  const float* b3 = (const float*)d_in[6];
  const float* Wi = (const float*)d_in[7];
  const float* Wh = (const float*)d_in[8];
  const float* lb = (const float*)d_in[9];
  const float* dw = (const float*)d_in[10];
  const float* db = (const float*)d_in[11];
  float* out = (float*)d_out;
  char* ws = (char*)d_ws;

  // ws (~194.8 MB <= proven 197): act | xgcA | xgcB | whP | cst
  const size_t ACT_BYTES = (size_t)B_SZ * T_OUT * HDIM * 2;   // 157.3 MB
  const size_t XGC_BYTES = (size_t)B_SZ * TC * GDIM * 2;      // 15.7 MB each
  const size_t WHP_BYTES = (size_t)5 * 192 * 1536 * 4;        // 5.9 MB
  f16*   act  = (f16*)ws;
  f16*   xgcA = (f16*)(ws + ACT_BYTES);
  f16*   xgcB = (f16*)(ws + ACT_BYTES + XGC_BYTES);
  f16x2* whP  = (f16x2*)(ws + ACT_BYTES + 2 * XGC_BYTES);
  float* cst  = (float*)(ws + ACT_BYTES + 2 * XGC_BYTES + WHP_BYTES);
  // y2 (32.8 MB) overlays xgcA+xgcB+head of whP; consumed before they're written.
  f16* y2 = xgcA;

  hipLaunchKernelGGL(conv12_kernel, dim3(B_SZ * T_IN / 256), dim3(256), 0, stream,
                     x, w1, b1, w2, b2, y2);
  hipLaunchKernelGGL(conv3_kernel, dim3(T_OUT / 16, B_SZ), dim3(384), 0, stream,
                     y2, w3, b3, act);
  hipLaunchKernelGGL(whcvt_kernel, dim3(5 * 192 * 1536 / 256), dim3(256), 0, stream,
                     Wh, whP);

  for (int l = 0; l < 5; ++l) {
    int rev = (l % 2 == 0) ? 1 : 0;
    const float* wi_p = Wi + (size_t)l * HDIM * GDIM;
    const f16x2* wh_p = whP + (size_t)l * 192 * 1536;
    const float* lb_p = lb + (size_t)l * GDIM;
    // prime chunk 0
    int lo0 = rev ? (T_OUT - TC) : 0;
    hipLaunchKernelGGL(gemm_xg_kernel, dim3(GDIM / 128, (B_SZ * TC) / 128), dim3(256), 0, stream,
                       act, wi_p, xgcA, lo0);
    for (int ci = 0; ci < NCHUNK; ++ci) {
      int lo_l = rev ? (T_OUT - (ci + 1) * TC) : (ci * TC);
      int do_gemm = (ci + 1 < NCHUNK) ? 1 : 0;
      int lo_g = do_gemm ? (rev ? (T_OUT - (ci + 2) * TC) : ((ci + 1) * TC)) : 0;
      f16* rd = (ci % 2 == 0) ? xgcA : xgcB;
      f16* wr = (ci % 2 == 0) ? xgcB : xgcA;
      hipLaunchKernelGGL(fused_kernel, dim3(256), dim3(768), 0, stream,
                         rd, wr, wh_p, lb_p, act, cst, wi_p,
                         lo_l, lo_g, rev, (ci == 0) ? 1 : 0, do_gemm);
    }
  }
  hipLaunchKernelGGL(dense_kernel, dim3((B_SZ * T_OUT) / 256), dim3(256), 0, stream,
                     act, dw, db, out);
}

// Round 10
// 69964.368 us; speedup vs baseline: 3.0350x; 1.1361x over previous
//
#include <hip/hip_runtime.h>
#include <math.h>

#define B_SZ 128
#define T_IN 8000
#define T_OUT 1600
#define HDIM 384
#define GDIM 1536   // 4*H
#define TC 40       // time chunk
#define NCHUNK (T_OUT / TC)   // 40
#define NTILES (12 * (B_SZ * TC / 128))   // 480 gemm tiles per chunk

typedef _Float16 f16;
typedef __attribute__((ext_vector_type(2))) _Float16 f16x2;
typedef __attribute__((ext_vector_type(4))) _Float16 f16x4;
typedef __attribute__((ext_vector_type(8))) _Float16 f16x8;

__device__ inline float fdot2(f16x2 a, f16x2 b, float c) {
#if __has_builtin(__builtin_amdgcn_fdot2)
  return __builtin_amdgcn_fdot2(a, b, c, false);
#else
  return fmaf((float)a[0], (float)b[0], fmaf((float)a[1], (float)b[1], c));
#endif
}

// ---------------------------------------------------------------------------
// conv1 (5,1,4) + silu + conv2 (5,4,16) + silu, fused. One thread per (b,t).
// ---------------------------------------------------------------------------
__global__ __launch_bounds__(256) void conv12_kernel(
    const float* __restrict__ x, const float* __restrict__ w1, const float* __restrict__ b1,
    const float* __restrict__ w2, const float* __restrict__ b2, f16* __restrict__ y2) {
  __shared__ float sw1[20], sb1[4], sw2[320], sb2[16];
  int tid = threadIdx.x;
  if (tid < 20) sw1[tid] = w1[tid];
  if (tid < 4)  sb1[tid] = b1[tid];
  if (tid < 16) sb2[tid] = b2[tid];
  for (int i = tid; i < 320; i += 256) sw2[i] = w2[i];
  __syncthreads();
  int flat = blockIdx.x * 256 + tid;
  int b = flat / T_IN, t = flat % T_IN;
  const float* xb = x + (size_t)b * T_IN;
  float xv[9];
#pragma unroll
  for (int d = 0; d < 9; ++d) {
    int tt = t + d - 4;
    xv[d] = (tt >= 0 && tt < T_IN) ? xb[tt] : 0.f;
  }
  float y1[5][4];
#pragma unroll
  for (int u = 0; u < 5; ++u) {
    int tau = t + u - 2;
    bool valid = (tau >= 0 && tau < T_IN);
#pragma unroll
    for (int co = 0; co < 4; ++co) {
      float a = sb1[co];
#pragma unroll
      for (int k = 0; k < 5; ++k) a = fmaf(xv[u + k], sw1[k * 4 + co], a);
      y1[u][co] = valid ? (a / (1.f + expf(-a))) : 0.f;
    }
  }
  f16x8 o0, o1;
#pragma unroll
  for (int co = 0; co < 16; ++co) {
    float a = sb2[co];
#pragma unroll
    for (int u = 0; u < 5; ++u)
#pragma unroll
      for (int ci = 0; ci < 4; ++ci)
        a = fmaf(y1[u][ci], sw2[(u * 4 + ci) * 16 + co], a);
    float sv = a / (1.f + expf(-a));
    if (co < 8) o0[co] = (f16)sv; else o1[co - 8] = (f16)sv;
  }
  f16x8* dst = (f16x8*)(y2 + (size_t)flat * 16);
  dst[0] = o0;
  dst[1] = o1;
}

// ---------------------------------------------------------------------------
// conv3: (19,16,384), stride 5, SAME (pad 7/7), + silu. fp16 in/out, fp32 math.
// ---------------------------------------------------------------------------
__global__ __launch_bounds__(384) void conv3_kernel(
    const f16* __restrict__ y2, const float* __restrict__ w3, const float* __restrict__ b3,
    f16* __restrict__ act) {
  __shared__ float in_s[94 * 16];
  int tid = threadIdx.x;
  int b = blockIdx.y;
  int t0 = blockIdx.x * 16;
  int base_t = t0 * 5 - 7;
  for (int i = tid; i < 94 * 16; i += 384) {
    int tau = i >> 4, ci = i & 15;
    int tt = base_t + tau;
    in_s[i] = (tt >= 0 && tt < T_IN) ? (float)y2[((size_t)b * T_IN + tt) * 16 + ci] : 0.f;
  }
  __syncthreads();
  int c = tid;
  float acc[16];
  float bv = b3[c];
#pragma unroll
  for (int tt = 0; tt < 16; ++tt) acc[tt] = bv;
  for (int kk = 0; kk < 19; ++kk) {
#pragma unroll
    for (int c4 = 0; c4 < 4; ++c4) {
      float wa = w3[(size_t)((kk * 16 + c4 * 4 + 0) * 384) + c];
      float wb = w3[(size_t)((kk * 16 + c4 * 4 + 1) * 384) + c];
      float wc = w3[(size_t)((kk * 16 + c4 * 4 + 2) * 384) + c];
      float wd = w3[(size_t)((kk * 16 + c4 * 4 + 3) * 384) + c];
#pragma unroll
      for (int tt = 0; tt < 16; ++tt) {
        const float4 iv = *(const float4*)&in_s[(tt * 5 + kk) * 16 + c4 * 4];
        acc[tt] = fmaf(iv.x, wa, acc[tt]);
        acc[tt] = fmaf(iv.y, wb, acc[tt]);
        acc[tt] = fmaf(iv.z, wc, acc[tt]);
        acc[tt] = fmaf(iv.w, wd, acc[tt]);
      }
    }
  }
#pragma unroll
  for (int tt = 0; tt < 16; ++tt) {
    float a = acc[tt];
    a = a / (1.f + expf(-a));
    act[((size_t)b * T_OUT + t0 + tt) * HDIM + c] = (f16)a;
  }
}

// ---------------------------------------------------------------------------
// Wh repack: whP[l][k2][c] = (Wh[l][2k2][c], Wh[l][2k2+1][c]) as fp16x2.
// ---------------------------------------------------------------------------
__global__ __launch_bounds__(256) void whcvt_kernel(
    const float* __restrict__ Wh, f16x2* __restrict__ whP) {
  size_t idx = (size_t)blockIdx.x * 256 + threadIdx.x;
  int l = (int)(idx / (192 * 1536));
  int rem = (int)(idx % (192 * 1536));
  int k2 = rem / 1536;
  int c = rem % 1536;
  const float* src = Wh + ((size_t)l * 384 + 2 * k2) * 1536 + c;
  f16x2 v;
  v[0] = (f16)src[0];
  v[1] = (f16)src[1536];
  whP[idx] = v;
}

// ---------------------------------------------------------------------------
// Standalone chunked xg GEMM (primes chunk 0 of each layer).
// ---------------------------------------------------------------------------
__global__ __launch_bounds__(256) void gemm_xg_kernel(
    const f16* __restrict__ act, const float* __restrict__ Bw,
    f16* __restrict__ C, int lo) {
  __shared__ f16x2 As2[8 * 136];
  __shared__ f16x2 Bs2[8 * 128];
  int tid = threadIdx.x;
  int n0 = blockIdx.x * 128;
  int m0 = blockIdx.y * 128;
  int am = tid >> 2;
  int ak = (tid & 3) * 4;
  int bk = tid >> 5;
  int bn = (tid & 31) * 4;
  int row0 = m0 + am, row1 = row0 + 64;
  const f16* Ap0 = act + ((size_t)(row0 / TC) * T_OUT + lo + row0 % TC) * HDIM + ak;
  const f16* Ap1 = act + ((size_t)(row1 / TC) * T_OUT + lo + row1 % TC) * HDIM + ak;
  const float* Bp = Bw + (size_t)(2 * bk) * GDIM + n0 + bn;
  f16x4 ra0 = *(const f16x4*)Ap0;
  f16x4 ra1 = *(const f16x4*)Ap1;
  float4 rb0 = *(const float4*)Bp;
  float4 rb1 = *(const float4*)(Bp + (size_t)GDIM);
  float acc[8][8];
#pragma unroll
  for (int i = 0; i < 8; ++i)
#pragma unroll
    for (int j = 0; j < 8; ++j) acc[i][j] = 0.f;
  int tx = tid & 15, ty = tid >> 4;
  for (int kt = 0; kt < 24; ++kt) {
    int ak2 = ak >> 1;
    As2[(ak2 + 0) * 136 + am] = (f16x2){ra0[0], ra0[1]};
    As2[(ak2 + 1) * 136 + am] = (f16x2){ra0[2], ra0[3]};
    As2[(ak2 + 0) * 136 + am + 64] = (f16x2){ra1[0], ra1[1]};
    As2[(ak2 + 1) * 136 + am + 64] = (f16x2){ra1[2], ra1[3]};
    Bs2[bk * 128 + bn + 0] = (f16x2){(f16)rb0.x, (f16)rb1.x};
    Bs2[bk * 128 + bn + 1] = (f16x2){(f16)rb0.y, (f16)rb1.y};
    Bs2[bk * 128 + bn + 2] = (f16x2){(f16)rb0.z, (f16)rb1.z};
    Bs2[bk * 128 + bn + 3] = (f16x2){(f16)rb0.w, (f16)rb1.w};
    __syncthreads();
    if (kt < 23) {
      Ap0 += 16; Ap1 += 16; Bp += (size_t)16 * GDIM;
      ra0 = *(const f16x4*)Ap0;
      ra1 = *(const f16x4*)Ap1;
      rb0 = *(const float4*)Bp;
      rb1 = *(const float4*)(Bp + (size_t)GDIM);
    }
#pragma unroll
    for (int k2 = 0; k2 < 8; ++k2) {
      f16x8 a0 = *(const f16x8*)&As2[k2 * 136 + ty * 4];
      f16x8 a1 = *(const f16x8*)&As2[k2 * 136 + 64 + ty * 4];
      f16x8 b0 = *(const f16x8*)&Bs2[k2 * 128 + tx * 4];
      f16x8 b1 = *(const f16x8*)&Bs2[k2 * 128 + 64 + tx * 4];
      f16x2 av[8], bv[8];
#pragma unroll
      for (int q = 0; q < 4; ++q) {
        av[q] = (f16x2){a0[2 * q], a0[2 * q + 1]};
        av[q + 4] = (f16x2){a1[2 * q], a1[2 * q + 1]};
        bv[q] = (f16x2){b0[2 * q], b0[2 * q + 1]};
        bv[q + 4] = (f16x2){b1[2 * q], b1[2 * q + 1]};
      }
#pragma unroll
      for (int i = 0; i < 8; ++i)
#pragma unroll
        for (int j = 0; j < 8; ++j) acc[i][j] = fdot2(av[i], bv[j], acc[i][j]);
    }
    __syncthreads();
  }
#pragma unroll
  for (int i = 0; i < 8; ++i) {
    int mi = (i < 4) ? (ty * 4 + i) : (64 + ty * 4 + i - 4);
    f16* Cp = C + (size_t)(m0 + mi) * GDIM + n0;
    f16x4 p0, p1;
    p0[0] = (f16)acc[i][0]; p0[1] = (f16)acc[i][1]; p0[2] = (f16)acc[i][2]; p0[3] = (f16)acc[i][3];
    p1[0] = (f16)acc[i][4]; p1[1] = (f16)acc[i][5]; p1[2] = (f16)acc[i][6]; p1[3] = (f16)acc[i][7];
    *(f16x4*)(Cp + tx * 4) = p0;
    *(f16x4*)(Cp + 64 + tx * 4) = p1;
  }
}

// ---------------------------------------------------------------------------
// FUSED kernel: 256 blocks x 768 threads.
//  blocks 0..63  : LSTM chunk at lo_l; 24/96 k2 of each thread's Wh slice
//                  cached in VGPRs (96 regs) across all TC steps.
//  blocks 64..255: GEMM for next chunk at lo_g; 3 sub-tiles/block; invalid
//                  subs skip work (wave-uniform guard) but join barriers.
// ---------------------------------------------------------------------------
union FusedSh {
  struct { f16x2 h2s[2][192]; float zsp[2][2][1536]; float bias_s[1536]; } L;
  struct { f16x2 As2[3][8 * 136]; f16x2 Bs2[3][8 * 128]; } G;
  char pad[57344];
};

__global__ __launch_bounds__(768, 1) void fused_kernel(
    const f16* __restrict__ xgc_rd, f16* __restrict__ xgc_wr,
    const f16x2* __restrict__ whP, const float* __restrict__ bias,
    f16* __restrict__ act, float* __restrict__ cst, const float* __restrict__ Wi,
    int lo_l, int lo_g, int reverse, int first, int do_gemm) {
  __shared__ FusedSh sh;
  int tid = threadIdx.x;

  if (blockIdx.x < 64) {
    // ================= LSTM branch =================
    int wid = blockIdx.x;
    int b0 = wid * 2;
    for (int i = tid; i < 1536; i += 768) sh.L.bias_s[i] = bias[i];
    int bl = tid / 384;
    int j = tid - bl * 384;
    int kap = bl, cq = j;
    int c4 = 4 * cq;
    float c_st;
    if (first) {
      c_st = 0.f;
      ((f16*)sh.L.h2s)[tid] = (f16)0.f;
    } else {
      int tprev = reverse ? (lo_l + TC) : (lo_l - 1);
      c_st = cst[(size_t)(b0 + bl) * HDIM + j];
      ((f16*)&sh.L.h2s[bl][0])[j] = act[((size_t)(b0 + bl) * T_OUT + tprev) * HDIM + j];
    }

    const f16x2* wcol = whP + c4 + (size_t)(96 * kap) * 1536;
    const int k2base = 96 * kap;

    // VGPR weight cache: k2 rel [0,24) of this thread's slice (96 VGPRs).
    f16x8 wreg[6][4];
#pragma unroll
    for (int q = 0; q < 6; ++q)
#pragma unroll
      for (int r = 0; r < 4; ++r)
        wreg[q][r] = *(const f16x8*)(wcol + (size_t)(4 * q + r) * 1536);
    __syncthreads();

    for (int s = 0; s < TC; ++s) {
      int t = reverse ? (lo_l + TC - 1 - s) : (lo_l + s);
      int tl = t - lo_l;
      float a0[4] = {0.f, 0.f, 0.f, 0.f};
      float a1[4] = {0.f, 0.f, 0.f, 0.f};
      // --- cached section: k2 rel [0,24) ---
#pragma unroll
      for (int q = 0; q < 6; ++q) {
        int k2b = k2base + 4 * q;
        f16x8 ha = *(const f16x8*)&sh.L.h2s[0][k2b];
        f16x8 hb = *(const f16x8*)&sh.L.h2s[1][k2b];
        f16x2 ha0 = {ha[0], ha[1]}, ha1 = {ha[2], ha[3]}, ha2 = {ha[4], ha[5]}, ha3 = {ha[6], ha[7]};
        f16x2 hb0 = {hb[0], hb[1]}, hb1 = {hb[2], hb[3]}, hb2 = {hb[4], hb[5]}, hb3 = {hb[6], hb[7]};
#pragma unroll
        for (int c = 0; c < 4; ++c) {
          f16x2 wc0 = {wreg[q][0][2 * c], wreg[q][0][2 * c + 1]};
          f16x2 wc1 = {wreg[q][1][2 * c], wreg[q][1][2 * c + 1]};
          f16x2 wc2 = {wreg[q][2][2 * c], wreg[q][2][2 * c + 1]};
          f16x2 wc3 = {wreg[q][3][2 * c], wreg[q][3][2 * c + 1]};
          a0[c] = fdot2(wc0, ha0, a0[c]);
          a1[c] = fdot2(wc0, hb0, a1[c]);
          a0[c] = fdot2(wc1, ha1, a0[c]);
          a1[c] = fdot2(wc1, hb1, a1[c]);
          a0[c] = fdot2(wc2, ha2, a0[c]);
          a1[c] = fdot2(wc2, hb2, a1[c]);
          a0[c] = fdot2(wc3, ha3, a0[c]);
          a1[c] = fdot2(wc3, hb3, a1[c]);
        }
      }
      // --- streamed section: k2 rel [24,96) ---
      const f16x2* wp = wcol + (size_t)24 * 1536;
#pragma unroll 2
      for (int q = 6; q < 24; ++q) {
        int k2b = k2base + 4 * q;
        f16x8 w0 = *(const f16x8*)(wp);
        f16x8 w1 = *(const f16x8*)(wp + 1536);
        f16x8 w2 = *(const f16x8*)(wp + 2 * 1536);
        f16x8 w3 = *(const f16x8*)(wp + 3 * 1536);
        f16x8 ha = *(const f16x8*)&sh.L.h2s[0][k2b];
        f16x8 hb = *(const f16x8*)&sh.L.h2s[1][k2b];
        f16x2 ha0 = {ha[0], ha[1]}, ha1 = {ha[2], ha[3]}, ha2 = {ha[4], ha[5]}, ha3 = {ha[6], ha[7]};
        f16x2 hb0 = {hb[0], hb[1]}, hb1 = {hb[2], hb[3]}, hb2 = {hb[4], hb[5]}, hb3 = {hb[6], hb[7]};
#pragma unroll
        for (int c = 0; c < 4; ++c) {
          f16x2 wc0 = {w0[2 * c], w0[2 * c + 1]};
          f16x2 wc1 = {w1[2 * c], w1[2 * c + 1]};
          f16x2 wc2 = {w2[2 * c], w2[2 * c + 1]};
          f16x2 wc3 = {w3[2 * c], w3[2 * c + 1]};
          a0[c] = fdot2(wc0, ha0, a0[c]);
          a1[c] = fdot2(wc0, hb0, a1[c]);
          a0[c] = fdot2(wc1, ha1, a0[c]);
          a1[c] = fdot2(wc1, hb1, a1[c]);
          a0[c] = fdot2(wc2, ha2, a0[c]);
          a1[c] = fdot2(wc2, hb2, a1[c]);
          a0[c] = fdot2(wc3, ha3, a0[c]);
          a1[c] = fdot2(wc3, hb3, a1[c]);
        }
        wp += 4 * 1536;
      }
      *(float4*)&sh.L.zsp[kap][0][c4] = make_float4(a0[0], a0[1], a0[2], a0[3]);
      *(float4*)&sh.L.zsp[kap][1][c4] = make_float4(a1[0], a1[1], a1[2], a1[3]);
      __syncthreads();
      {
        float zi = sh.L.zsp[0][bl][j]        + sh.L.zsp[1][bl][j]        + sh.L.bias_s[j];
        float zf = sh.L.zsp[0][bl][384 + j]  + sh.L.zsp[1][bl][384 + j]  + sh.L.bias_s[384 + j];
        float zg = sh.L.zsp[0][bl][768 + j]  + sh.L.zsp[1][bl][768 + j]  + sh.L.bias_s[768 + j];
        float zo = sh.L.zsp[0][bl][1152 + j] + sh.L.zsp[1][bl][1152 + j] + sh.L.bias_s[1152 + j];
        const f16* xp = xgc_rd + ((size_t)(b0 + bl) * TC + tl) * GDIM + j;
        zi += (float)xp[0];
        zf += (float)xp[384];
        zg += (float)xp[768];
        zo += (float)xp[1152];
        float ig = 1.f / (1.f + expf(-zi));
        float fg = 1.f / (1.f + expf(-zf));
        float gv = tanhf(zg);
        float og = 1.f / (1.f + expf(-zo));
        c_st = fg * c_st + ig * gv;
        float hv = og * tanhf(c_st);
        f16 h16v = (f16)hv;
        ((f16*)&sh.L.h2s[bl][0])[j] = h16v;
        act[((size_t)(b0 + bl) * T_OUT + t) * HDIM + j] = h16v;
      }
      __syncthreads();
    }
    cst[(size_t)(b0 + bl) * HDIM + j] = c_st;
  } else {
    // ================= GEMM worker branch =================
    if (!do_gemm) return;
    int wid = blockIdx.x - 64;        // 0..191
    int sub = tid >> 8;               // 0..2 (wave-uniform)
    int stid = tid & 255;
    int tileid = wid + 192 * sub;     // 0..575
    bool valid = (tileid < NTILES);
    int tclamp = valid ? tileid : 0;
    int n0 = (tclamp % 12) * 128;
    int m0 = (tclamp / 12) * 128;
    f16x2* As2 = &sh.G.As2[sub][0];
    f16x2* Bs2 = &sh.G.Bs2[sub][0];
    int am = stid >> 2;
    int ak = (stid & 3) * 4;
    int bk = stid >> 5;
    int bn = (stid & 31) * 4;
    int row0 = m0 + am, row1 = row0 + 64;
    const f16* Ap0 = act + ((size_t)(row0 / TC) * T_OUT + lo_g + row0 % TC) * HDIM + ak;
    const f16* Ap1 = act + ((size_t)(row1 / TC) * T_OUT + lo_g + row1 % TC) * HDIM + ak;
    const float* Bp = Wi + (size_t)(2 * bk) * GDIM + n0 + bn;
    f16x4 ra0 = {}, ra1 = {};
    float4 rb0 = {}, rb1 = {};
    if (valid) {
      ra0 = *(const f16x4*)Ap0;
      ra1 = *(const f16x4*)Ap1;
      rb0 = *(const float4*)Bp;
      rb1 = *(const float4*)(Bp + (size_t)GDIM);
    }
    float acc[8][8];
#pragma unroll
    for (int i = 0; i < 8; ++i)
#pragma unroll
      for (int j = 0; j < 8; ++j) acc[i][j] = 0.f;
    int tx = stid & 15, ty = stid >> 4;
    for (int kt = 0; kt < 24; ++kt) {
      if (valid) {
        int ak2 = ak >> 1;
        As2[(ak2 + 0) * 136 + am] = (f16x2){ra0[0], ra0[1]};
        As2[(ak2 + 1) * 136 + am] = (f16x2){ra0[2], ra0[3]};
        As2[(ak2 + 0) * 136 + am + 64] = (f16x2){ra1[0], ra1[1]};
        As2[(ak2 + 1) * 136 + am + 64] = (f16x2){ra1[2], ra1[3]};
        Bs2[bk * 128 + bn + 0] = (f16x2){(f16)rb0.x, (f16)rb1.x};
        Bs2[bk * 128 + bn + 1] = (f16x2){(f16)rb0.y, (f16)rb1.y};
        Bs2[bk * 128 + bn + 2] = (f16x2){(f16)rb0.z, (f16)rb1.z};
        Bs2[bk * 128 + bn + 3] = (f16x2){(f16)rb0.w, (f16)rb1.w};
      }
      __syncthreads();
      if (valid) {
        if (kt < 23) {
          Ap0 += 16; Ap1 += 16; Bp += (size_t)16 * GDIM;
          ra0 = *(const f16x4*)Ap0;
          ra1 = *(const f16x4*)Ap1;
          rb0 = *(const float4*)Bp;
          rb1 = *(const float4*)(Bp + (size_t)GDIM);
        }
#pragma unroll
        for (int k2 = 0; k2 < 8; ++k2) {
          f16x8 a0 = *(const f16x8*)&As2[k2 * 136 + ty * 4];
          f16x8 a1 = *(const f16x8*)&As2[k2 * 136 + 64 + ty * 4];
          f16x8 b0 = *(const f16x8*)&Bs2[k2 * 128 + tx * 4];
          f16x8 b1 = *(const f16x8*)&Bs2[k2 * 128 + 64 + tx * 4];
          f16x2 av[8], bv[8];
#pragma unroll
          for (int q = 0; q < 4; ++q) {
            av[q] = (f16x2){a0[2 * q], a0[2 * q + 1]};
            av[q + 4] = (f16x2){a1[2 * q], a1[2 * q + 1]};
            bv[q] = (f16x2){b0[2 * q], b0[2 * q + 1]};
            bv[q + 4] = (f16x2){b1[2 * q], b1[2 * q + 1]};
          }
#pragma unroll
          for (int i = 0; i < 8; ++i)
#pragma unroll
            for (int j = 0; j < 8; ++j) acc[i][j] = fdot2(av[i], bv[j], acc[i][j]);
        }
      }
      __syncthreads();
    }
    if (valid) {
#pragma unroll
      for (int i = 0; i < 8; ++i) {
        int mi = (i < 4) ? (ty * 4 + i) : (64 + ty * 4 + i - 4);
        f16* Cp = xgc_wr + (size_t)(m0 + mi) * GDIM + n0;
        f16x4 p0, p1;
        p0[0] = (f16)acc[i][0]; p0[1] = (f16)acc[i][1]; p0[2] = (f16)acc[i][2]; p0[3] = (f16)acc[i][3];
        p1[0] = (f16)acc[i][4]; p1[1] = (f16)acc[i][5]; p1[2] = (f16)acc[i][6]; p1[3] = (f16)acc[i][7];
        *(f16x4*)(Cp + tx * 4) = p0;
        *(f16x4*)(Cp + 64 + tx * 4) = p1;
      }
    }
  }
}

// ---------------------------------------------------------------------------
// dense: out(204800,5) = h(204800,384 fp16) @ W(384,5) + b  (fp32 out)
// ---------------------------------------------------------------------------
__global__ __launch_bounds__(256) void dense_kernel(
    const f16* __restrict__ h, const float* __restrict__ dw,
    const float* __restrict__ db, float* __restrict__ out) {
  __shared__ float ws_[1920];
  __shared__ float bs[5];
  int tid = threadIdx.x;
  for (int i = tid; i < 1920; i += 256) ws_[i] = dw[i];
  if (tid < 5) bs[tid] = db[tid];
  __syncthreads();
  size_t flat = (size_t)blockIdx.x * 256 + tid;
  const f16* hp = h + flat * HDIM;
  float acc[5];
#pragma unroll
  for (int o = 0; o < 5; ++o) acc[o] = bs[o];
  for (int d = 0; d < HDIM; d += 4) {
    f16x4 hv = *(const f16x4*)(hp + d);
#pragma unroll
    for (int o = 0; o < 5; ++o) {
      acc[o] = fmaf((float)hv[0], ws_[(d + 0) * 5 + o], acc[o]);
      acc[o] = fmaf((float)hv[1], ws_[(d + 1) * 5 + o], acc[o]);
      acc[o] = fmaf((float)hv[2], ws_[(d + 2) * 5 + o], acc[o]);
      acc[o] = fmaf((float)hv[3], ws_[(d + 3) * 5 + o], acc[o]);
    }
  }
  float* op = out + flat * 5;
#pragma unroll
  for (int o = 0; o < 5; ++o) op[o] = acc[o];
}

// ---------------------------------------------------------------------------
extern "C" void kernel_launch(void* const* d_in, const int* in_sizes, int n_in,
                              void* d_out, int out_size, void* d_ws, size_t ws_size,
                              hipStream_t stream) {
  const float* x  = (const float*)d_in[0];
  const float* w1 = (const float*)d_in[1];
  const float* b1 = (const float*)d_in[2];
  const float* w2 = (const float*)d_in[3];
  const float* b2 = (const float*)d_in[4];
  const float* w3 = (const float*)d_in[5];
  const float* b3 = (const float*)d_in[6];
  const float* Wi = (const float*)d_in[7];
  const float* Wh = (const float*)d_in[8];
  const float* lb = (const float*)d_in[9];
  const float* dw = (const float*)d_in[10];
  const float* db = (const float*)d_in[11];
  float* out = (float*)d_out;
  char* ws = (char*)d_ws;

  // ws (~194.8 MB <= proven 197): act | xgcA | xgcB | whP | cst
  const size_t ACT_BYTES = (size_t)B_SZ * T_OUT * HDIM * 2;   // 157.3 MB
  const size_t XGC_BYTES = (size_t)B_SZ * TC * GDIM * 2;      // 15.7 MB each
  const size_t WHP_BYTES = (size_t)5 * 192 * 1536 * 4;        // 5.9 MB
  f16*   act  = (f16*)ws;
  f16*   xgcA = (f16*)(ws + ACT_BYTES);
  f16*   xgcB = (f16*)(ws + ACT_BYTES + XGC_BYTES);
  f16x2* whP  = (f16x2*)(ws + ACT_BYTES + 2 * XGC_BYTES);
  float* cst  = (float*)(ws + ACT_BYTES + 2 * XGC_BYTES + WHP_BYTES);
  f16* y2 = xgcA;  // alias: consumed before xgc/whP are written

  hipLaunchKernelGGL(conv12_kernel, dim3(B_SZ * T_IN / 256), dim3(256), 0, stream,
                     x, w1, b1, w2, b2, y2);
  hipLaunchKernelGGL(conv3_kernel, dim3(T_OUT / 16, B_SZ), dim3(384), 0, stream,
                     y2, w3, b3, act);
  hipLaunchKernelGGL(whcvt_kernel, dim3(5 * 192 * 1536 / 256), dim3(256), 0, stream,
                     Wh, whP);

  for (int l = 0; l < 5; ++l) {
    int rev = (l % 2 == 0) ? 1 : 0;
    const float* wi_p = Wi + (size_t)l * HDIM * GDIM;
    const f16x2* wh_p = whP + (size_t)l * 192 * 1536;
    const float* lb_p = lb + (size_t)l * GDIM;
    int lo0 = rev ? (T_OUT - TC) : 0;
    hipLaunchKernelGGL(gemm_xg_kernel, dim3(GDIM / 128, (B_SZ * TC) / 128), dim3(256), 0, stream,
                       act, wi_p, xgcA, lo0);
    for (int ci = 0; ci < NCHUNK; ++ci) {
      int lo_l = rev ? (T_OUT - (ci + 1) * TC) : (ci * TC);
      int do_gemm = (ci + 1 < NCHUNK) ? 1 : 0;
      int lo_g = do_gemm ? (rev ? (T_OUT - (ci + 2) * TC) : ((ci + 1) * TC)) : 0;
      f16* rd = (ci % 2 == 0) ? xgcA : xgcB;
      f16* wr = (ci % 2 == 0) ? xgcB : xgcA;
      hipLaunchKernelGGL(fused_kernel, dim3(256), dim3(768), 0, stream,
                         rd, wr, wh_p, lb_p, act, cst, wi_p,
                         lo_l, lo_g, rev, (ci == 0) ? 1 : 0, do_gemm);
    }
  }
  hipLaunchKernelGGL(dense_kernel, dim3((B_SZ * T_OUT) / 256), dim3(256), 0, stream,
                     act, dw, db, out);
}